// Round 14
// baseline (4218.723 us; speedup 1.0000x reference)
//
#include <hip/hip_runtime.h>
#include <hip/hip_bf16.h>

typedef __attribute__((ext_vector_type(8))) short short8;
typedef __attribute__((ext_vector_type(4))) float f32x4;
typedef _Float16 f16x8 __attribute__((ext_vector_type(8)));

#define NLAYER 12
#define NTOK   6304
#define MPAD   6400
#define CONVM  6272

#define QELE     ((size_t)384*208*64)
#define VELE     ((size_t)384*80*232)

// per-layer weight strides (elements)
#define WS_QKV ((size_t)2304*768)
#define WS_WO  ((size_t)768*768)
#define WS_W12 ((size_t)4096*768)
#define WS_W3  ((size_t)768*2048)

static constexpr size_t AL(size_t x){ return (x + 511) & ~(size_t)511; }
static constexpr size_t B_COS    = 0;
static constexpr size_t B_SIN    = AL(B_COS    + (size_t)197*32*4);
static constexpr size_t B_WPT    = AL(B_SIN    + (size_t)197*32*4);
static constexpr size_t B_APATCH = AL(B_WPT    + (size_t)768*1024*2);
static constexpr size_t B_WQKVT  = AL(B_APATCH + (size_t)CONVM*1024*2);
static constexpr size_t B_WOT    = AL(B_WQKVT  + WS_QKV*NLAYER*2);
static constexpr size_t B_W12T   = AL(B_WOT    + WS_WO*NLAYER*2);
static constexpr size_t B_W3T    = AL(B_W12T   + WS_W12*NLAYER*2);
static constexpr size_t B_TOK    = AL(B_W3T    + WS_W3*NLAYER*2);
static constexpr size_t B_ACTA   = AL(B_TOK    + (size_t)NTOK*768*2);
static constexpr size_t B_ACTB   = AL(B_ACTA   + (size_t)MPAD*768*2);
static constexpr size_t B_GOUT   = AL(B_ACTB   + (size_t)MPAD*2048*2);
static constexpr size_t B_QB     = AL(B_GOUT   + (size_t)MPAD*768*4);
static constexpr size_t B_KB     = AL(B_QB     + QELE*2);
static constexpr size_t B_VT     = AL(B_KB     + QELE*2);
static constexpr size_t B_QTB    = AL(B_VT     + VELE*2);
static constexpr size_t B_KTB    = AL(B_QTB    + (size_t)384*208*4);
static constexpr size_t B_END    = AL(B_KTB    + (size_t)384*208*4);

typedef __attribute__((address_space(1))) unsigned int gu32;
typedef __attribute__((address_space(3))) unsigned int lu32;
__device__ __forceinline__ void gld16(const void* g, void* l) {
  __builtin_amdgcn_global_load_lds((const gu32*)g, (lu32*)l, 16, 0, 0);
}

// ---------------- helpers ----------------
__device__ __forceinline__ float bsum(float v, float* red) {
  #pragma unroll
  for (int m = 32; m; m >>= 1) v += __shfl_xor(v, m, 64);
  __syncthreads();
  if ((threadIdx.x & 63) == 0) red[threadIdx.x >> 6] = v;
  __syncthreads();
  return red[0] + red[1] + red[2] + red[3];
}

__device__ __forceinline__ ushort h_us(float v) {
  _Float16 h = (_Float16)v;
  return *(ushort*)&h;
}
__device__ __forceinline__ float us_f(ushort u) {
  return (float)*(const _Float16*)&u;
}

// bijective XCD-chunked remap (m204)
__device__ __forceinline__ void xcd_remap(int& bx, int& by) {
  int gx = gridDim.x, gy = gridDim.y;
  int nwg = gx * gy;
  int orig = blockIdx.y * gx + blockIdx.x;
  int q = nwg >> 3, r = nwg & 7;
  int xcd = orig & 7, loc = orig >> 3;
  int wg = (xcd < r ? xcd * (q + 1) : r * (q + 1) + (xcd - r) * q) + loc;
  bx = wg / gy;
  by = wg % gy;
}

// ---------------- RoPE tables ----------------
__global__ void k_rope_tab(float* __restrict__ cosb, float* __restrict__ sinb) {
  int idx = blockIdx.x * 256 + threadIdx.x;
  if (idx >= 197 * 32) return;
  int p = idx >> 5, j = idx & 31;
  float cv, sv;
  if (p == 0) { cv = 1.f; sv = 0.f; }
  else {
    int pp = p - 1;
    int iy = pp / 14, ix = pp - iy * 14;
    int pos = (j < 16) ? iy : ix;
    int f   = (j < 16) ? j  : j - 16;
    float inv = powf(100.f, -(float)f / 16.f);
    float a = (float)pos * inv;
    cv = cosf(a); sv = sinf(a);
  }
  cosb[idx] = cv; sinb[idx] = sv;
}

// ---------------- 32x32 LDS-tiled transpose (prologue Wp only) ----------------
__device__ __forceinline__ void tpose_tile(const float* __restrict__ src, ushort* __restrict__ dst,
                                           int K, int N, int ldd, int imode, int tk, int tn) {
  __shared__ float ts[32][33];
  int t = threadIdx.x;
  int rr = t >> 3, c4 = (t & 7) * 4;
  int k0 = tk * 32, n0 = tn * 32;
  int k = k0 + rr, nb = n0 + c4;
  const float* sp = src + (size_t)k * N + nb;
  if (k < K && nb + 3 < N && (((size_t)sp & 15) == 0)) {
    float4 v = *(const float4*)sp;
    ts[rr][c4] = v.x; ts[rr][c4 + 1] = v.y; ts[rr][c4 + 2] = v.z; ts[rr][c4 + 3] = v.w;
  } else {
    #pragma unroll
    for (int e = 0; e < 4; ++e) {
      int n = nb + e;
      ts[rr][c4 + e] = (k < K && n < N) ? src[(size_t)k * N + n] : 0.f;
    }
  }
  __syncthreads();
  int c = n0 + rr;
  int drow = (imode == 0) ? c : (16 * (c >> 3) + (c & 7) + (imode == 2 ? 8 : 0));
  ushort4 o;
  #pragma unroll
  for (int e = 0; e < 4; ++e) {
    _Float16 hv = (_Float16)ts[c4 + e][rr];
    ((ushort*)&o)[e] = *(ushort*)&hv;
  }
  *(ushort4*)&dst[(size_t)drow * ldd + k0 + c4] = o;
}

__global__ __launch_bounds__(256) void k_tpose(const float* __restrict__ src, ushort* __restrict__ dst,
                                               int K, int N, int ktiles, int ldd) {
  int tk = blockIdx.x % ktiles, tn = blockIdx.x / ktiles;
  tpose_tile(src, dst, K, N, ldd, 0, tk, tn);
}

// ---------------- 64x32 tile: float4 reads, 16B short8 writes (128B/row) ----------------
__device__ __forceinline__ void tpose_tile64(const float* __restrict__ src, ushort* __restrict__ dst,
                                             int K, int N, int ldd, int imode, int tk, int tn) {
  __shared__ float ts[64][33];
  int t = threadIdx.x;
  int row = t >> 3;            // 0..31
  int c4 = (t & 7) * 4;        // 0..28
  int k0 = tk * 64, n0 = tn * 32;
  #pragma unroll
  for (int ph = 0; ph < 2; ++ph) {
    int kr = row + ph * 32;
    int k = k0 + kr;
    int nb = n0 + c4;
    const float* sp = src + (size_t)k * N + nb;
    if (k < K && nb + 3 < N && (((size_t)sp & 15) == 0)) {
      float4 v = *(const float4*)sp;
      ts[kr][c4] = v.x; ts[kr][c4 + 1] = v.y; ts[kr][c4 + 2] = v.z; ts[kr][c4 + 3] = v.w;
    } else {
      #pragma unroll
      for (int e = 0; e < 4; ++e) {
        int n = nb + e;
        ts[kr][c4 + e] = (k < K && n < N) ? src[(size_t)k * N + n] : 0.f;
      }
    }
  }
  __syncthreads();
  int rr2 = t >> 3;            // output row within n-tile
  int kc8 = (t & 7) * 8;
  int c = n0 + rr2;
  int drow = (imode == 0) ? c : (16 * (c >> 3) + (c & 7) + (imode == 2 ? 8 : 0));
  short8 o8;
  #pragma unroll
  for (int e = 0; e < 8; ++e) {
    _Float16 hv = (_Float16)ts[kc8 + e][rr2];
    o8[e] = *(short*)&hv;
  }
  *(short8*)&dst[(size_t)drow * ldd + k0 + kc8] = o8;
}

// all 7 weight transposes x all 12 layers, 3456 tiles/layer
__global__ __launch_bounds__(256) void k_wprep12(const float* __restrict__ Wq, const float* __restrict__ Wk,
                                                 const float* __restrict__ Wv, const float* __restrict__ Wo,
                                                 const float* __restrict__ W1, const float* __restrict__ W2,
                                                 const float* __restrict__ W3,
                                                 ushort* __restrict__ wqkvt, ushort* __restrict__ wot,
                                                 ushort* __restrict__ w12t, ushort* __restrict__ w3t) {
  int gt = blockIdx.x;
  int l = gt / 3456;
  int tile = gt - l * 3456;
  const float* q  = Wq + (size_t)l * 767 * 768;
  const float* kk = Wk + (size_t)l * 767 * 768;
  const float* v  = Wv + (size_t)l * 767 * 768;
  const float* o  = Wo + (size_t)l * 768 * 767;
  const float* w1 = W1 + (size_t)l * 767 * 2048;
  const float* w2 = W2 + (size_t)l * 767 * 2048;
  const float* w3 = W3 + (size_t)l * 2048 * 767;
  ushort* dqkv = wqkvt + (size_t)l * WS_QKV;
  ushort* dwo  = wot   + (size_t)l * WS_WO;
  ushort* dw12 = w12t  + (size_t)l * WS_W12;
  ushort* dw3  = w3t   + (size_t)l * WS_W3;
  const float* src; ushort* dst;
  int K, N, ktiles, ldd, imode = 0, tl;
  if (tile < 864) {
    int jb = tile / 288; tl = tile % 288;
    ktiles = 12; ldd = 768; K = 767; N = 768;
    src = (jb == 0) ? q : (jb == 1) ? kk : v;
    dst = dqkv + (size_t)jb * 768 * 768;
  } else if (tile < 1152) {
    tl = tile - 864;
    ktiles = 12; ldd = 768; K = 768; N = 767; src = o; dst = dwo;
  } else if (tile < 2688) {
    int jb = (tile - 1152) / 768; tl = (tile - 1152) % 768;
    ktiles = 12; ldd = 768; K = 767; N = 2048; dst = dw12;
    src = jb ? w2 : w1; imode = jb ? 2 : 1;
  } else {
    tl = tile - 2688; ktiles = 32; ldd = 2048; K = 2048; N = 767; src = w3; dst = dw3;
  }
  int tk = tl % ktiles, tn = tl / ktiles;
  tpose_tile64(src, dst, K, N, ldd, imode, tk, tn);
}

// ---------------- im2col with Lorentz time channel, fp16 ----------------
__global__ __launch_bounds__(256) void k_im2col(const float* __restrict__ x, ushort* __restrict__ ap) {
  int r = blockIdx.x;
  int b = r / 196, pi = r - b * 196;
  int py = pi / 14, px = pi - py * 14;
  int t = threadIdx.x;
  int ph = t >> 4, pw = t & 15;
  int iy = py * 16 + ph, ix = px * 16 + pw;
  size_t base = ((size_t)b * 3 * 224 + iy) * 224 + ix;
  float x0 = x[base];
  float x1 = x[base + 224 * 224];
  float x2 = x[base + 2 * 224 * 224];
  float tv = sqrtf(fmaxf(x0 * x0 + x1 * x1 + x2 * x2 + 1.f, 1e-6f));
  size_t o = (size_t)r * 1024 + t * 4;
  ap[o] = h_us(tv); ap[o + 1] = h_us(x0); ap[o + 2] = h_us(x1); ap[o + 3] = h_us(x2);
}

// ---------------- 128-tile fp16 GEMM (single-buffer 2-barrier, hoisted addressing) ----------------
// MODE 0: f32 C; 1: fused silu -> fp16 H; 3: fp16 H
template<int MODE>
__global__ __launch_bounds__(256, 5) void k_gemmh(const ushort* __restrict__ A, const ushort* __restrict__ Bt,
                                                  float* __restrict__ C, ushort* __restrict__ H,
                                                  int N, int K) {
  __shared__ ushort sA[128 * 64];
  __shared__ ushort sB[128 * 64];
  int bx, by;
  xcd_remap(bx, by);
  int m0 = bx * 128, n0 = by * 128;
  int t = threadIdx.x;
  int w = t >> 6, l = t & 63;
  int wm = (w >> 1) * 64, wn = (w & 1) * 64;
  int lr = l & 15, hi = l >> 4;

  // hoisted staging pointers (advance by 64 elements per k-step) + fixed LDS dests
  const ushort* apg[4];
  const ushort* bpg[4];
  ushort* sda[4];
  ushort* sdb[4];
  #pragma unroll
  for (int i = 0; i < 4; ++i) {
    int fl = i * 256 + t;
    int r = fl >> 3, c = fl & 7;
    int cs = c ^ (r & 7);
    apg[i] = A + (size_t)(m0 + r) * K + cs * 8;
    bpg[i] = Bt + (size_t)(n0 + r) * K + cs * 8;
    sda[i] = &sA[fl * 8];
    sdb[i] = &sB[fl * 8];
  }
  // hoisted LDS read offsets (loop-invariant)
  int offA[4][2], offB[4][2];
  #pragma unroll
  for (int q = 0; q < 4; ++q) {
    int ra = wm + q * 16 + lr, rb = wn + q * 16 + lr;
    #pragma unroll
    for (int h = 0; h < 2; ++h) {
      offA[q][h] = ra * 64 + ((h * 4 + hi) ^ (ra & 7)) * 8;
      offB[q][h] = rb * 64 + ((h * 4 + hi) ^ (rb & 7)) * 8;
    }
  }

  f32x4 acc[4][4] = {};
  for (int k0 = 0; k0 < K; k0 += 64) {
    #pragma unroll
    for (int i = 0; i < 4; ++i) {
      gld16(apg[i], sda[i]);
      gld16(bpg[i], sdb[i]);
      apg[i] += 64;
      bpg[i] += 64;
    }
    __syncthreads();
    f16x8 af[4][2], bfr[4][2];
    #pragma unroll
    for (int q = 0; q < 4; ++q)
      #pragma unroll
      for (int h = 0; h < 2; ++h) {
        af[q][h]  = *(const f16x8*)&sA[offA[q][h]];
        bfr[q][h] = *(const f16x8*)&sB[offB[q][h]];
      }
    #pragma unroll
    for (int mi = 0; mi < 4; ++mi)
      #pragma unroll
      for (int ni = 0; ni < 4; ++ni) {
        acc[mi][ni] = __builtin_amdgcn_mfma_f32_16x16x32_f16(af[mi][0], bfr[ni][0], acc[mi][ni], 0, 0, 0);
        acc[mi][ni] = __builtin_amdgcn_mfma_f32_16x16x32_f16(af[mi][1], bfr[ni][1], acc[mi][ni], 0, 0, 0);
      }
    __syncthreads();
  }
  int rr = hi * 4, cc = lr;
  if (MODE == 1) {
    #pragma unroll
    for (int mi = 0; mi < 4; ++mi)
      #pragma unroll
      for (int ni = 0; ni < 4; ++ni) {
        int g = (n0 + wn + ni * 16) >> 4;
        #pragma unroll
        for (int j = 0; j < 4; ++j) {
          float v = acc[mi][ni][j];
          float p = __shfl_xor(v, 8);
          float u1 = (cc < 8) ? v : p;
          float u2 = (cc < 8) ? p : v;
          float hv = u1 / (1.f + __expf(-u1)) * u2;
          if (cc < 8)
            H[(size_t)(m0 + wm + mi * 16 + rr + j) * 2048 + g * 8 + cc] = h_us(hv);
        }
      }
  } else if (MODE == 3) {
    #pragma unroll
    for (int mi = 0; mi < 4; ++mi)
      #pragma unroll
      for (int ni = 0; ni < 4; ++ni)
        #pragma unroll
        for (int j = 0; j < 4; ++j)
          H[(size_t)(m0 + wm + mi * 16 + rr + j) * N + (n0 + wn + ni * 16 + cc)] = h_us(acc[mi][ni][j]);
  } else {
    #pragma unroll
    for (int mi = 0; mi < 4; ++mi)
      #pragma unroll
      for (int ni = 0; ni < 4; ++ni)
        #pragma unroll
        for (int j = 0; j < 4; ++j)
          C[(size_t)(m0 + wm + mi * 16 + rr + j) * N + (n0 + wn + ni * 16 + cc)] = acc[mi][ni][j];
  }
}

// ---------------- 256-tile 8-phase counted-vmcnt fp16 GEMM. MODE 2: QKV epilogue ----------------
template<int MODE>
__global__ __launch_bounds__(512, 2) void k_g256(const ushort* __restrict__ A, const ushort* __restrict__ Bt,
                                                 ushort* __restrict__ H, int N, int K,
                                                 ushort* __restrict__ qbuf, ushort* __restrict__ kbuf,
                                                 ushort* __restrict__ vtb,
                                                 float* __restrict__ qtb, float* __restrict__ ktb,
                                                 const float* __restrict__ cosb, const float* __restrict__ sinb) {
  __shared__ ushort sA[2][2][256 * 32];
  __shared__ ushort sB[2][2][256 * 32];
  const int t = threadIdx.x;
  const int w = t >> 6, l = t & 63;
  const int wr = w >> 2, wc = w & 3;
  const int lr = l & 15, hi4 = l >> 4;
  int bx, by;
  xcd_remap(bx, by);
  const int m0 = bx * 256, n0 = by * 256;

  auto stageA = [&](int kt, int kh, int buf) {
    #pragma unroll
    for (int ii = 0; ii < 2; ++ii) {
      int q = ii * 512 + t;
      int r = q >> 2, ci = q & 3;
      gld16(&A[(size_t)(m0 + r) * K + kt * 64 + kh * 32 + ((ci ^ ((r >> 1) & 3)) * 8)], &sA[buf][kh][q * 8]);
    }
  };
  auto stageB = [&](int kt, int kh, int buf) {
    #pragma unroll
    for (int ii = 0; ii < 2; ++ii) {
      int q = ii * 512 + t;
      int r = q >> 2, ci = q & 3;
      gld16(&Bt[(size_t)(n0 + r) * K + kt * 64 + kh * 32 + ((ci ^ ((r >> 1) & 3)) * 8)], &sB[buf][kh][q * 8]);
    }
  };

  f32x4 acc[8][4] = {};
  auto ldA = [&](int buf, int ks, int G, f16x8* fr) {
    #pragma unroll
    for (int mi = 0; mi < 4; ++mi) {
      int r = wr * 128 + (G * 4 + mi) * 16 + lr;
      fr[mi] = *(const f16x8*)&sA[buf][ks][(r * 4 + (hi4 ^ ((r >> 1) & 3))) * 8];
    }
  };
  auto ldB = [&](int buf, int ks, f16x8* fr) {
    #pragma unroll
    for (int ni = 0; ni < 4; ++ni) {
      int r = wc * 64 + ni * 16 + lr;
      fr[ni] = *(const f16x8*)&sB[buf][ks][(r * 4 + (hi4 ^ ((r >> 1) & 3))) * 8];
    }
  };
  auto mmaG = [&](int G, f16x8* a, f16x8* b) {
    __builtin_amdgcn_s_setprio(1);
    #pragma unroll
    for (int mi = 0; mi < 4; ++mi)
      #pragma unroll
      for (int ni = 0; ni < 4; ++ni)
        acc[G * 4 + mi][ni] = __builtin_amdgcn_mfma_f32_16x16x32_f16(a[mi], b[ni], acc[G * 4 + mi][ni], 0, 0, 0);
    __builtin_amdgcn_s_setprio(0);
  };

  const int NT = K >> 6;
  const int NI = NT >> 1;
  stageA(0, 0, 0); stageB(0, 0, 0); stageA(0, 1, 0); stageB(0, 1, 0);

  for (int i = 0; i < NI; ++i) {
    const int T1 = 2 * i + 1, T2 = 2 * i + 2;
    const bool last = (i == NI - 1);
    f16x8 a0[4], a1[4], b0[4], b1[4];
    asm volatile("s_waitcnt vmcnt(4)" ::: "memory");
    __builtin_amdgcn_sched_barrier(0);
    __builtin_amdgcn_s_barrier();
    ldA(0, 0, 0, a0); ldB(0, 0, b0);
    stageA(T1, 0, 1);
    mmaG(0, a0, b0);
    ldA(0, 0, 1, a1);
    stageB(T1, 0, 1);
    mmaG(1, a1, b0);
    asm volatile("s_waitcnt vmcnt(4)" ::: "memory");
    __builtin_amdgcn_sched_barrier(0);
    __builtin_amdgcn_s_barrier();
    ldA(0, 1, 0, a0); ldB(0, 1, b1);
    stageA(T1, 1, 1);
    mmaG(0, a0, b1);
    ldA(0, 1, 1, a1);
    stageB(T1, 1, 1);
    mmaG(1, a1, b1);
    asm volatile("s_waitcnt vmcnt(4)" ::: "memory");
    __builtin_amdgcn_sched_barrier(0);
    __builtin_amdgcn_s_barrier();
    ldA(1, 0, 0, a0); ldB(1, 0, b0);
    if (!last) stageA(T2, 0, 0);
    mmaG(0, a0, b0);
    ldA(1, 0, 1, a1);
    if (!last) stageB(T2, 0, 0);
    mmaG(1, a1, b0);
    if (last) { asm volatile("s_waitcnt vmcnt(0)" ::: "memory"); }
    else      { asm volatile("s_waitcnt vmcnt(4)" ::: "memory"); }
    __builtin_amdgcn_sched_barrier(0);
    __builtin_amdgcn_s_barrier();
    ldA(1, 1, 0, a0); ldB(1, 1, b1);
    if (!last) stageA(T2, 1, 0);
    mmaG(0, a0, b1);
    ldA(1, 1, 1, a1);
    if (!last) stageB(T2, 1, 0);
    mmaG(1, a1, b1);
  }

  if (MODE == 2) {
    int secBase = n0 + wc * 64;
    int sec = secBase / 768;
    int hh = (secBase - sec * 768) >> 6;
    #pragma unroll
    for (int mi = 0; mi < 8; ++mi) {
      float nrm[4];
      #pragma unroll
      for (int j = 0; j < 4; ++j) {
        float ss = 0.f;
        #pragma unroll
        for (int ni = 0; ni < 4; ++ni) ss += acc[mi][ni][j] * acc[mi][ni][j];
        #pragma unroll
        for (int m = 8; m; m >>= 1) ss += __shfl_xor(ss, m, 64);
        nrm[j] = sqrtf(fmaxf(ss + 1.f, 1e-6f));
      }
      #pragma unroll
      for (int j = 0; j < 4; ++j) {
        int m = m0 + wr * 128 + mi * 16 + hi4 * 4 + j;
        if (m < NTOK) {
          int b = m / 197, nn = m - b * 197;
          int bh = b * 12 + hh;
          if (sec == 2) {
            size_t vo = (size_t)bh * 80 * 232;
            if (lr == 0) vtb[vo + nn] = h_us(nrm[j]);
            #pragma unroll
            for (int ni = 0; ni < 4; ++ni) {
              int e = ni * 16 + lr;
              vtb[vo + (size_t)(1 + e) * 232 + nn] = h_us(acc[mi][ni][j]);
            }
          } else {
            float* tb = (sec == 0) ? qtb : ktb;
            ushort* ob = (sec == 0) ? qbuf : kbuf;
            if (lr == 0) tb[(size_t)bh * 208 + nn] = nrm[j];
            size_t rowb = ((size_t)bh * 208 + nn) * 64;
            #pragma unroll
            for (int ni = 0; ni < 4; ++ni) {
              int d = ni * 16 + lr;
              float v = acc[mi][ni][j];
              float p = __shfl_xor(v, 1);
              int j2 = d >> 1;
              float cz = cosb[nn * 32 + j2], sz = sinb[nn * 32 + j2];
              float rv = ((lr & 1) == 0) ? (v * cz - p * sz) : (p * sz + v * cz);
              ob[rowb + d] = h_us(rv);
            }
          }
        }
      }
    }
  }
}

// ---------------- build tokens -> fp16 trunk ----------------
__global__ __launch_bounds__(256) void k_build_tok(const float* __restrict__ feat, const float* __restrict__ cls,
                                                   ushort* __restrict__ tok) {
  __shared__ float red[8];
  int r = blockIdx.x;
  int b = r / 197, i = r - b * 197;
  int t = threadIdx.x;
  const float* src = (i == 0) ? cls : (feat + (size_t)(b * 196 + i - 1) * 768);
  float v0 = src[t], v1 = src[256 + t], v2 = (t < 255) ? src[512 + t] : 0.f;
  float qs = bsum(v0 * v0 + v1 * v1 + v2 * v2, red);
  ushort* tp = tok + (size_t)r * 768;
  if (t == 0) tp[0] = h_us(sqrtf(fmaxf(qs + 1.f, 1e-6f)));
  tp[1 + t] = h_us(v0); tp[257 + t] = h_us(v1); if (t < 255) tp[513 + t] = h_us(v2);
}

// ---------------- lorentz layernorm (fp16 trunk) -> fp16 (pad col 767 = 0) ----------------
__global__ __launch_bounds__(256) void k_ln(const ushort* __restrict__ tok, const float* __restrict__ g,
                                            const float* __restrict__ bb, ushort* __restrict__ out) {
  __shared__ float red[8];
  int r = blockIdx.x, t = threadIdx.x;
  const ushort* xp = tok + (size_t)r * 768;
  float v0 = us_f(xp[1 + t]), v1 = us_f(xp[257 + t]), v2 = (t < 255) ? us_f(xp[513 + t]) : 0.f;
  float s = bsum(v0 + v1 + v2, red);
  float q = bsum(v0 * v0 + v1 * v1 + v2 * v2, red);
  float mu = s * (1.f / 767.f);
  float rstd = rsqrtf(fmaxf(q * (1.f / 767.f) - mu * mu, 0.f) + 1e-6f);
  size_t o = (size_t)r * 768;
  out[o + t]       = h_us((v0 - mu) * rstd * g[t]       + bb[t]);
  out[o + 256 + t] = h_us((v1 - mu) * rstd * g[256 + t] + bb[256 + t]);
  if (t < 255)
    out[o + 512 + t] = h_us((v2 - mu) * rstd * g[512 + t] + bb[512 + t]);
  if (t == 255) out[o + 767] = 0;
}

// ---------------- MFMA attention, barrier-free: K/kt/V from L2, per-wave P in LDS ----------------
__global__ __launch_bounds__(128) void k_attn(const ushort* __restrict__ qbuf,
                                              const float* __restrict__ qtb,
                                              const ushort* __restrict__ kbuf,
                                              const float* __restrict__ ktb,
                                              const ushort* __restrict__ vtb,
                                              ushort* __restrict__ outa) {
  __shared__ ushort sP[2][16 * 248];
  int bxt = blockIdx.x, bh = blockIdx.y;
  int b = bh / 12, hd = bh - b * 12;
  int t = threadIdx.x, w = t >> 6, l = t & 63;
  int rt = bxt * 2 + w;
  if (rt >= 13) return;
  int lr = l & 15, hi4 = l >> 4;
  const ushort* qg = qbuf + (size_t)bh * 208 * 64;
  const ushort* kg = kbuf + (size_t)bh * 208 * 64;
  const ushort* vg = vtb + (size_t)bh * 80 * 232;
  const float*  ktp = ktb + (size_t)bh * 208;
  const float invs = 0.03608439182435161f;
  ushort* pw = &sP[w][0];

  int qrow = (rt * 16 + lr) * 64 + hi4 * 8;
  f16x8 q0 = *(const f16x8*)&qg[qrow];
  f16x8 q1 = *(const f16x8*)&qg[qrow + 32];
  float qt4[4];
  #pragma unroll
  for (int j = 0; j < 4; ++j) qt4[j] = qtb[(size_t)bh * 208 + rt * 16 + hi4 * 4 + j];
  f32x4 acc[13];
  #pragma unroll
  for (int nt = 0; nt < 13; ++nt) {
    int kr = (nt * 16 + lr) * 64 + hi4 * 8;
    f16x8 k0 = *(const f16x8*)&kg[kr];
    f16x8 k1 = *(const f16x8*)&kg[kr + 32];
    acc[nt] = (f32x4){0.f, 0.f, 0.f, 0.f};
    acc[nt] = __builtin_amdgcn_mfma_f32_16x16x32_f16(q0, k0, acc[nt], 0, 0, 0);
    acc[nt] = __builtin_amdgcn_mfma_f32_16x16x32_f16(q1, k1, acc[nt], 0, 0, 0);
  }
  float mx[4] = {-1e30f, -1e30f, -1e30f, -1e30f};
  #pragma unroll
  for (int nt = 0; nt < 13; ++nt) {
    int cI = nt * 16 + lr;
    float ktc = ktp[cI];
    bool valid = (cI < 197);
    #pragma unroll
    for (int j = 0; j < 4; ++j) {
      float s = (2.f + 2.f * (acc[nt][j] - qt4[j] * ktc)) * invs;
      acc[nt][j] = s;
      if (valid) mx[j] = fmaxf(mx[j], s);
    }
  }
  #pragma unroll
  for (int j = 0; j < 4; ++j)
    #pragma unroll
    for (int m = 8; m; m >>= 1) mx[j] = fmaxf(mx[j], __shfl_xor(mx[j], m, 64));
  #pragma unroll
  for (int nt = 0; nt < 14; ++nt) {
    int cI = nt * 16 + lr;
    #pragma unroll
    for (int j = 0; j < 4; ++j) {
      float p = (nt < 13 && cI < 197) ? __expf(acc[nt][j] - mx[j]) : 0.f;
      pw[(hi4 * 4 + j) * 248 + cI] = h_us(p);
    }
  }
  f32x4 accO[5];
  #pragma unroll
  for (int et = 0; et < 5; ++et) accO[et] = (f32x4){0.f, 0.f, 0.f, 0.f};
  #pragma unroll
  for (int ks = 0; ks < 7; ++ks) {
    f16x8 pa = *(const f16x8*)&pw[lr * 248 + ks * 32 + hi4 * 8];
    #pragma unroll
    for (int et = 0; et < 5; ++et) {
      int er = et * 16 + lr;
      f16x8 bv = *(const f16x8*)&vg[(er > 64 ? 64 : er) * 232 + ks * 32 + hi4 * 8];
      accO[et] = __builtin_amdgcn_mfma_f32_16x16x32_f16(pa, bv, accO[et], 0, 0, 0);
    }
  }
  float ssq[4] = {0.f, 0.f, 0.f, 0.f};
  #pragma unroll
  for (int et = 0; et < 4; ++et)
    #pragma unroll
    for (int j = 0; j < 4; ++j) ssq[j] += accO[et][j] * accO[et][j];
  if (lr == 0) {
    #pragma unroll
    for (int j = 0; j < 4; ++j) ssq[j] += accO[4][j] * accO[4][j];
  }
  #pragma unroll
  for (int j = 0; j < 4; ++j)
    #pragma unroll
    for (int m = 8; m; m >>= 1) ssq[j] += __shfl_xor(ssq[j], m, 64);
  float rf4[4];
  #pragma unroll
  for (int j = 0; j < 4; ++j) {
    float o0 = __shfl(accO[0][j], (l & 48));
    rf4[j] = rsqrtf(fmaxf(2.f * o0 * o0 - ssq[j], 1e-6f));
  }
  #pragma unroll
  for (int et = 0; et < 5; ++et) {
    int e = et * 16 + lr;
    if (e == 0 || e >= 65) continue;
    #pragma unroll
    for (int j = 0; j < 4; ++j) {
      int n = rt * 16 + hi4 * 4 + j;
      if (n < 197)
        outa[((size_t)(b * 197 + n)) * 768 + hd * 64 + (e - 1)] = h_us(accO[et][j] * rf4[j]);
    }
  }
}

// ---------------- fused lresnet + LN: wave-per-row, barrier-free ----------------
template<int FIN>
__global__ __launch_bounds__(256) void k_resnet_ln(ushort* __restrict__ tok, const ushort* __restrict__ s,
                                                   const float* __restrict__ wyp, int l,
                                                   const float* __restrict__ g, const float* __restrict__ bb,
                                                   ushort* __restrict__ out16, float* __restrict__ out32) {
  int w = threadIdx.x >> 6, lane = threadIdx.x & 63;
  int r = blockIdx.x * 4 + w;         // NTOK = 1576*4 exactly
  float wv = wyp[l];
  const ushort* sp = s + (size_t)r * 768;
  ushort* tp = tok + (size_t)r * 768;
  float sv[12], zv[12];
  float qs = 0.f;
  #pragma unroll
  for (int i = 0; i < 12; ++i) {
    int j = lane + 64 * i;
    float si = (j < 767) ? us_f(sp[j]) : 0.f;
    sv[i] = si; qs += si * si;
  }
  #pragma unroll
  for (int m = 32; m; m >>= 1) qs += __shfl_xor(qs, m, 64);
  float at = sqrtf(fmaxf(qs + 1.f, 1e-6f));
  float zs = 0.f;
  #pragma unroll
  for (int i = 0; i < 12; ++i) {
    int j = lane + 64 * i;
    float zi = (j < 767) ? (us_f(tp[1 + j]) + wv * sv[i]) : 0.f;
    zv[i] = zi; zs += zi * zi;
  }
  #pragma unroll
  for (int m = 32; m; m >>= 1) zs += __shfl_xor(zs, m, 64);
  float zt = us_f(tp[0]) + wv * at;
  float rf = rsqrtf(fmaxf(zt * zt - zs, 1e-6f));
  float sm = 0.f, sq = 0.f;
  #pragma unroll
  for (int i = 0; i < 12; ++i) {
    float ni = zv[i] * rf;
    zv[i] = ni;
    int j = lane + 64 * i;
    if (j < 767) tp[1 + j] = h_us(ni);
    sm += ni; sq += ni * ni;
  }
  if (lane == 0) tp[0] = h_us(zt * rf);
  #pragma unroll
  for (int m = 32; m; m >>= 1) { sm += __shfl_xor(sm, m, 64); sq += __shfl_xor(sq, m, 64); }
  float mu = sm * (1.f / 767.f);
  float rstd = rsqrtf(fmaxf(sq * (1.f / 767.f) - mu * mu, 0.f) + 1e-6f);
  if (FIN) {
    float yv[12];
    float qq = 0.f;
    #pragma unroll
    for (int i = 0; i < 12; ++i) {
      int j = lane + 64 * i;
      float y = (j < 767) ? ((zv[i] - mu) * rstd * g[j] + bb[j]) : 0.f;
      yv[i] = y; qq += y * y;
    }
    #pragma unroll
    for (int m = 32; m; m >>= 1) qq += __shfl_xor(qq, m, 64);
    float* op = out32 + (size_t)r * 768;
    #pragma unroll
    for (int i = 0; i < 12; ++i) {
      int j = lane + 64 * i;
      if (j < 767) op[1 + j] = yv[i];
    }
    if (lane == 0) op[0] = sqrtf(fmaxf(qq + 1.f, 1e-6f));
  } else {
    size_t o = (size_t)r * 768;
    #pragma unroll
    for (int i = 0; i < 12; ++i) {
      int j = lane + 64 * i;
      if (j < 767) out16[o + j] = h_us((zv[i] - mu) * rstd * g[j] + bb[j]);
      else if (j == 767) out16[o + 767] = 0;
    }
  }
}

extern "C" void kernel_launch(void* const* d_in, const int* in_sizes, int n_in,
                              void* d_out, int out_size, void* d_ws, size_t ws_size,
                              hipStream_t stream) {
  const float* x     = (const float*)d_in[0];
  const float* cls_s = (const float*)d_in[1];
  const float* Wp    = (const float*)d_in[2];
  const float* ln1g  = (const float*)d_in[3];
  const float* ln1b  = (const float*)d_in[4];
  const float* Wq    = (const float*)d_in[5];
  const float* Wk    = (const float*)d_in[6];
  const float* Wv    = (const float*)d_in[7];
  const float* Wo    = (const float*)d_in[8];
  const float* ln2g  = (const float*)d_in[9];
  const float* ln2b  = (const float*)d_in[10];
  const float* W1    = (const float*)d_in[11];
  const float* W2    = (const float*)d_in[12];
  const float* W3    = (const float*)d_in[13];
  const float* wy1   = (const float*)d_in[14];
  const float* wy2   = (const float*)d_in[15];
  const float* lnfg  = (const float*)d_in[16];
  const float* lnfb  = (const float*)d_in[17];

  if (ws_size < B_END) return;

  char* ws = (char*)d_ws;
  float*  cosb   = (float*)(ws + B_COS);
  float*  sinb   = (float*)(ws + B_SIN);
  ushort* wpt    = (ushort*)(ws + B_WPT);
  ushort* apatch = (ushort*)(ws + B_APATCH);
  ushort* wqkvt  = (ushort*)(ws + B_WQKVT);
  ushort* wot    = (ushort*)(ws + B_WOT);
  ushort* w12t   = (ushort*)(ws + B_W12T);
  ushort* w3t    = (ushort*)(ws + B_W3T);
  ushort* tok    = (ushort*)(ws + B_TOK);
  ushort* acta   = (ushort*)(ws + B_ACTA);
  ushort* actb   = (ushort*)(ws + B_ACTB);
  float*  gout   = (float*)(ws + B_GOUT);
  ushort* gouth  = (ushort*)(ws + B_GOUT);
  ushort* qbuf   = (ushort*)(ws + B_QB);
  ushort* kbuf   = (ushort*)(ws + B_KB);
  ushort* vtb    = (ushort*)(ws + B_VT);
  float*  qtb    = (float*)(ws + B_QTB);
  float*  ktb    = (float*)(ws + B_KTB);

  // only V pads must be zero (P=0 x garbage would still contribute via PV MFMA).
  hipMemsetAsync(vtb, 0, VELE * 2, stream);

  k_rope_tab<<<25, 256, 0, stream>>>(cosb, sinb);
  k_tpose<<<32 * 24, 256, 0, stream>>>(Wp, wpt, 1024, 767, 32, 1024);
  k_im2col<<<CONVM, 256, 0, stream>>>(x, apatch);
  k_wprep12<<<3456 * NLAYER, 256, 0, stream>>>(Wq, Wk, Wv, Wo, W1, W2, W3, wqkvt, wot, w12t, w3t);
  k_gemmh<0><<<dim3(49, 6), 256, 0, stream>>>(apatch, wpt, gout, nullptr, 768, 1024);
  k_build_tok<<<NTOK, 256, 0, stream>>>(gout, cls_s, tok);
  k_ln<<<NTOK, 256, 0, stream>>>(tok, ln1g, ln1b, acta);

  for (int l = 0; l < NLAYER; ++l) {
    const ushort* wq_l  = wqkvt + (size_t)l * WS_QKV;
    const ushort* wo_l  = wot   + (size_t)l * WS_WO;
    const ushort* w12_l = w12t  + (size_t)l * WS_W12;
    const ushort* w3_l  = w3t   + (size_t)l * WS_W3;

    k_g256<2><<<dim3(25, 9), 512, 0, stream>>>(acta, wq_l, nullptr, 2304, 768,
                                               qbuf, kbuf, vtb, qtb, ktb, cosb, sinb);
    k_attn<<<dim3(7, 384), 128, 0, stream>>>(qbuf, qtb, kbuf, ktb, vtb, acta);
    k_gemmh<3><<<dim3(50, 6), 256, 0, stream>>>(acta, wo_l, nullptr, gouth, 768, 768);
    k_resnet_ln<0><<<1576, 256, 0, stream>>>(tok, gouth, wy1, l,
                                             ln2g + (size_t)l * 767, ln2b + (size_t)l * 767, acta, nullptr);

    k_gemmh<1><<<dim3(50, 32), 256, 0, stream>>>(acta, w12_l, nullptr, actb, 4096, 768);
    k_gemmh<3><<<dim3(50, 6), 256, 0, stream>>>(actb, w3_l, nullptr, gouth, 768, 2048);
    if (l < NLAYER - 1)
      k_resnet_ln<0><<<1576, 256, 0, stream>>>(tok, gouth, wy2, l,
                                               ln1g + (size_t)(l + 1) * 767, ln1b + (size_t)(l + 1) * 767,
                                               acta, nullptr);
    else
      k_resnet_ln<1><<<1576, 256, 0, stream>>>(tok, gouth, wy2, l, lnfg, lnfb, nullptr, (float*)d_out);
  }
}

// Round 15
// 3133.012 us; speedup vs baseline: 1.3465x; 1.3465x over previous
//
#include <hip/hip_runtime.h>
#include <hip/hip_bf16.h>

typedef __attribute__((ext_vector_type(8))) short short8;
typedef __attribute__((ext_vector_type(4))) float f32x4;
typedef _Float16 f16x8 __attribute__((ext_vector_type(8)));

#define NLAYER 12
#define NTOK   6304
#define MPAD   6400
#define CONVM  6272

#define QELE     ((size_t)384*208*64)
#define VELE     ((size_t)384*80*232)

// per-layer weight strides (elements)
#define WS_QKV ((size_t)2304*768)
#define WS_WO  ((size_t)768*768)
#define WS_W12 ((size_t)4096*768)
#define WS_W3  ((size_t)768*2048)

static constexpr size_t AL(size_t x){ return (x + 511) & ~(size_t)511; }
static constexpr size_t B_COS    = 0;
static constexpr size_t B_SIN    = AL(B_COS    + (size_t)197*32*4);
static constexpr size_t B_WPT    = AL(B_SIN    + (size_t)197*32*4);
static constexpr size_t B_APATCH = AL(B_WPT    + (size_t)768*1024*2);
static constexpr size_t B_WQKVT  = AL(B_APATCH + (size_t)CONVM*1024*2);
static constexpr size_t B_WOT    = AL(B_WQKVT  + WS_QKV*NLAYER*2);
static constexpr size_t B_W12T   = AL(B_WOT    + WS_WO*NLAYER*2);
static constexpr size_t B_W3T    = AL(B_W12T   + WS_W12*NLAYER*2);
static constexpr size_t B_TOK    = AL(B_W3T    + WS_W3*NLAYER*2);
static constexpr size_t B_ACTA   = AL(B_TOK    + (size_t)NTOK*768*2);
static constexpr size_t B_ACTB   = AL(B_ACTA   + (size_t)MPAD*768*2);
static constexpr size_t B_GOUT   = AL(B_ACTB   + (size_t)MPAD*2048*2);
static constexpr size_t B_QB     = AL(B_GOUT   + (size_t)MPAD*768*4);
static constexpr size_t B_KB     = AL(B_QB     + QELE*2);
static constexpr size_t B_VT     = AL(B_KB     + QELE*2);
static constexpr size_t B_QTB    = AL(B_VT     + VELE*2);
static constexpr size_t B_KTB    = AL(B_QTB    + (size_t)384*208*4);
static constexpr size_t B_END    = AL(B_KTB    + (size_t)384*208*4);

typedef __attribute__((address_space(1))) unsigned int gu32;
typedef __attribute__((address_space(3))) unsigned int lu32;
__device__ __forceinline__ void gld16(const void* g, void* l) {
  __builtin_amdgcn_global_load_lds((const gu32*)g, (lu32*)l, 16, 0, 0);
}

// ---------------- helpers ----------------
__device__ __forceinline__ float bsum(float v, float* red) {
  #pragma unroll
  for (int m = 32; m; m >>= 1) v += __shfl_xor(v, m, 64);
  __syncthreads();
  if ((threadIdx.x & 63) == 0) red[threadIdx.x >> 6] = v;
  __syncthreads();
  return red[0] + red[1] + red[2] + red[3];
}

__device__ __forceinline__ ushort h_us(float v) {
  _Float16 h = (_Float16)v;
  return *(ushort*)&h;
}
__device__ __forceinline__ float us_f(ushort u) {
  return (float)*(const _Float16*)&u;
}

// bijective XCD-chunked remap (m204)
__device__ __forceinline__ void xcd_remap(int& bx, int& by) {
  int gx = gridDim.x, gy = gridDim.y;
  int nwg = gx * gy;
  int orig = blockIdx.y * gx + blockIdx.x;
  int q = nwg >> 3, r = nwg & 7;
  int xcd = orig & 7, loc = orig >> 3;
  int wg = (xcd < r ? xcd * (q + 1) : r * (q + 1) + (xcd - r) * q) + loc;
  bx = wg / gy;
  by = wg % gy;
}

// ---------------- RoPE tables ----------------
__global__ void k_rope_tab(float* __restrict__ cosb, float* __restrict__ sinb) {
  int idx = blockIdx.x * 256 + threadIdx.x;
  if (idx >= 197 * 32) return;
  int p = idx >> 5, j = idx & 31;
  float cv, sv;
  if (p == 0) { cv = 1.f; sv = 0.f; }
  else {
    int pp = p - 1;
    int iy = pp / 14, ix = pp - iy * 14;
    int pos = (j < 16) ? iy : ix;
    int f   = (j < 16) ? j  : j - 16;
    float inv = powf(100.f, -(float)f / 16.f);
    float a = (float)pos * inv;
    cv = cosf(a); sv = sinf(a);
  }
  cosb[idx] = cv; sinb[idx] = sv;
}

// ---------------- 32x32 LDS-tiled transpose (prologue Wp only) ----------------
__device__ __forceinline__ void tpose_tile(const float* __restrict__ src, ushort* __restrict__ dst,
                                           int K, int N, int ldd, int imode, int tk, int tn) {
  __shared__ float ts[32][33];
  int t = threadIdx.x;
  int rr = t >> 3, c4 = (t & 7) * 4;
  int k0 = tk * 32, n0 = tn * 32;
  int k = k0 + rr, nb = n0 + c4;
  const float* sp = src + (size_t)k * N + nb;
  if (k < K && nb + 3 < N && (((size_t)sp & 15) == 0)) {
    float4 v = *(const float4*)sp;
    ts[rr][c4] = v.x; ts[rr][c4 + 1] = v.y; ts[rr][c4 + 2] = v.z; ts[rr][c4 + 3] = v.w;
  } else {
    #pragma unroll
    for (int e = 0; e < 4; ++e) {
      int n = nb + e;
      ts[rr][c4 + e] = (k < K && n < N) ? src[(size_t)k * N + n] : 0.f;
    }
  }
  __syncthreads();
  int c = n0 + rr;
  int drow = (imode == 0) ? c : (16 * (c >> 3) + (c & 7) + (imode == 2 ? 8 : 0));
  ushort4 o;
  #pragma unroll
  for (int e = 0; e < 4; ++e) {
    _Float16 hv = (_Float16)ts[c4 + e][rr];
    ((ushort*)&o)[e] = *(ushort*)&hv;
  }
  *(ushort4*)&dst[(size_t)drow * ldd + k0 + c4] = o;
}

__global__ __launch_bounds__(256) void k_tpose(const float* __restrict__ src, ushort* __restrict__ dst,
                                               int K, int N, int ktiles, int ldd) {
  int tk = blockIdx.x % ktiles, tn = blockIdx.x / ktiles;
  tpose_tile(src, dst, K, N, ldd, 0, tk, tn);
}

// ---------------- 64x32 tile: float4 reads, 16B short8 writes (128B/row) ----------------
__device__ __forceinline__ void tpose_tile64(const float* __restrict__ src, ushort* __restrict__ dst,
                                             int K, int N, int ldd, int imode, int tk, int tn) {
  __shared__ float ts[64][33];
  int t = threadIdx.x;
  int row = t >> 3;            // 0..31
  int c4 = (t & 7) * 4;        // 0..28
  int k0 = tk * 64, n0 = tn * 32;
  #pragma unroll
  for (int ph = 0; ph < 2; ++ph) {
    int kr = row + ph * 32;
    int k = k0 + kr;
    int nb = n0 + c4;
    const float* sp = src + (size_t)k * N + nb;
    if (k < K && nb + 3 < N && (((size_t)sp & 15) == 0)) {
      float4 v = *(const float4*)sp;
      ts[kr][c4] = v.x; ts[kr][c4 + 1] = v.y; ts[kr][c4 + 2] = v.z; ts[kr][c4 + 3] = v.w;
    } else {
      #pragma unroll
      for (int e = 0; e < 4; ++e) {
        int n = nb + e;
        ts[kr][c4 + e] = (k < K && n < N) ? src[(size_t)k * N + n] : 0.f;
      }
    }
  }
  __syncthreads();
  int rr2 = t >> 3;            // output row within n-tile
  int kc8 = (t & 7) * 8;
  int c = n0 + rr2;
  int drow = (imode == 0) ? c : (16 * (c >> 3) + (c & 7) + (imode == 2 ? 8 : 0));
  short8 o8;
  #pragma unroll
  for (int e = 0; e < 8; ++e) {
    _Float16 hv = (_Float16)ts[kc8 + e][rr2];
    o8[e] = *(short*)&hv;
  }
  *(short8*)&dst[(size_t)drow * ldd + k0 + kc8] = o8;
}

// all 7 weight transposes x all 12 layers, 3456 tiles/layer
__global__ __launch_bounds__(256) void k_wprep12(const float* __restrict__ Wq, const float* __restrict__ Wk,
                                                 const float* __restrict__ Wv, const float* __restrict__ Wo,
                                                 const float* __restrict__ W1, const float* __restrict__ W2,
                                                 const float* __restrict__ W3,
                                                 ushort* __restrict__ wqkvt, ushort* __restrict__ wot,
                                                 ushort* __restrict__ w12t, ushort* __restrict__ w3t) {
  int gt = blockIdx.x;
  int l = gt / 3456;
  int tile = gt - l * 3456;
  const float* q  = Wq + (size_t)l * 767 * 768;
  const float* kk = Wk + (size_t)l * 767 * 768;
  const float* v  = Wv + (size_t)l * 767 * 768;
  const float* o  = Wo + (size_t)l * 768 * 767;
  const float* w1 = W1 + (size_t)l * 767 * 2048;
  const float* w2 = W2 + (size_t)l * 767 * 2048;
  const float* w3 = W3 + (size_t)l * 2048 * 767;
  ushort* dqkv = wqkvt + (size_t)l * WS_QKV;
  ushort* dwo  = wot   + (size_t)l * WS_WO;
  ushort* dw12 = w12t  + (size_t)l * WS_W12;
  ushort* dw3  = w3t   + (size_t)l * WS_W3;
  const float* src; ushort* dst;
  int K, N, ktiles, ldd, imode = 0, tl;
  if (tile < 864) {
    int jb = tile / 288; tl = tile % 288;
    ktiles = 12; ldd = 768; K = 767; N = 768;
    src = (jb == 0) ? q : (jb == 1) ? kk : v;
    dst = dqkv + (size_t)jb * 768 * 768;
  } else if (tile < 1152) {
    tl = tile - 864;
    ktiles = 12; ldd = 768; K = 768; N = 767; src = o; dst = dwo;
  } else if (tile < 2688) {
    int jb = (tile - 1152) / 768; tl = (tile - 1152) % 768;
    ktiles = 12; ldd = 768; K = 767; N = 2048; dst = dw12;
    src = jb ? w2 : w1; imode = jb ? 2 : 1;
  } else {
    tl = tile - 2688; ktiles = 32; ldd = 2048; K = 2048; N = 767; src = w3; dst = dw3;
  }
  int tk = tl % ktiles, tn = tl / ktiles;
  tpose_tile64(src, dst, K, N, ldd, imode, tk, tn);
}

// ---------------- im2col with Lorentz time channel, fp16 ----------------
__global__ __launch_bounds__(256) void k_im2col(const float* __restrict__ x, ushort* __restrict__ ap) {
  int r = blockIdx.x;
  int b = r / 196, pi = r - b * 196;
  int py = pi / 14, px = pi - py * 14;
  int t = threadIdx.x;
  int ph = t >> 4, pw = t & 15;
  int iy = py * 16 + ph, ix = px * 16 + pw;
  size_t base = ((size_t)b * 3 * 224 + iy) * 224 + ix;
  float x0 = x[base];
  float x1 = x[base + 224 * 224];
  float x2 = x[base + 2 * 224 * 224];
  float tv = sqrtf(fmaxf(x0 * x0 + x1 * x1 + x2 * x2 + 1.f, 1e-6f));
  size_t o = (size_t)r * 1024 + t * 4;
  ap[o] = h_us(tv); ap[o + 1] = h_us(x0); ap[o + 2] = h_us(x1); ap[o + 3] = h_us(x2);
}

// ---------------- 128-tile fp16 GEMM (single-buffer 2-barrier, round-13 proven). ----------------
// MODE 0: f32 C; 1: fused silu -> fp16 H; 3: fp16 H
template<int MODE>
__global__ __launch_bounds__(256) void k_gemmh(const ushort* __restrict__ A, const ushort* __restrict__ Bt,
                                               float* __restrict__ C, ushort* __restrict__ H,
                                               int N, int K) {
  __shared__ ushort sA[128 * 64];
  __shared__ ushort sB[128 * 64];
  int bx, by;
  xcd_remap(bx, by);
  int m0 = bx * 128, n0 = by * 128;
  int t = threadIdx.x;
  int w = t >> 6, l = t & 63;
  int wm = (w >> 1) * 64, wn = (w & 1) * 64;
  int lr = l & 15, hi = l >> 4;
  f32x4 acc[4][4] = {};
  for (int k0 = 0; k0 < K; k0 += 64) {
    #pragma unroll
    for (int i = 0; i < 4; ++i) {
      int fl = i * 256 + t;
      int r = fl >> 3, c = fl & 7;
      int cs = c ^ (r & 7);
      gld16(&A[(size_t)(m0 + r) * K + k0 + cs * 8], &sA[fl * 8]);
      gld16(&Bt[(size_t)(n0 + r) * K + k0 + cs * 8], &sB[fl * 8]);
    }
    __syncthreads();
    f16x8 af[4][2], bfr[4][2];
    #pragma unroll
    for (int q = 0; q < 4; ++q) {
      int ra = wm + q * 16 + lr, rb = wn + q * 16 + lr;
      #pragma unroll
      for (int h = 0; h < 2; ++h) {
        af[q][h]  = *(const f16x8*)&sA[ra * 64 + ((h * 4 + hi) ^ (ra & 7)) * 8];
        bfr[q][h] = *(const f16x8*)&sB[rb * 64 + ((h * 4 + hi) ^ (rb & 7)) * 8];
      }
    }
    #pragma unroll
    for (int mi = 0; mi < 4; ++mi)
      #pragma unroll
      for (int ni = 0; ni < 4; ++ni) {
        acc[mi][ni] = __builtin_amdgcn_mfma_f32_16x16x32_f16(af[mi][0], bfr[ni][0], acc[mi][ni], 0, 0, 0);
        acc[mi][ni] = __builtin_amdgcn_mfma_f32_16x16x32_f16(af[mi][1], bfr[ni][1], acc[mi][ni], 0, 0, 0);
      }
    __syncthreads();
  }
  int rr = hi * 4, cc = lr;
  if (MODE == 1) {
    #pragma unroll
    for (int mi = 0; mi < 4; ++mi)
      #pragma unroll
      for (int ni = 0; ni < 4; ++ni) {
        int g = (n0 + wn + ni * 16) >> 4;
        #pragma unroll
        for (int j = 0; j < 4; ++j) {
          float v = acc[mi][ni][j];
          float p = __shfl_xor(v, 8);
          float u1 = (cc < 8) ? v : p;
          float u2 = (cc < 8) ? p : v;
          float hv = u1 / (1.f + __expf(-u1)) * u2;
          if (cc < 8)
            H[(size_t)(m0 + wm + mi * 16 + rr + j) * 2048 + g * 8 + cc] = h_us(hv);
        }
      }
  } else if (MODE == 3) {
    #pragma unroll
    for (int mi = 0; mi < 4; ++mi)
      #pragma unroll
      for (int ni = 0; ni < 4; ++ni)
        #pragma unroll
        for (int j = 0; j < 4; ++j)
          H[(size_t)(m0 + wm + mi * 16 + rr + j) * N + (n0 + wn + ni * 16 + cc)] = h_us(acc[mi][ni][j]);
  } else {
    #pragma unroll
    for (int mi = 0; mi < 4; ++mi)
      #pragma unroll
      for (int ni = 0; ni < 4; ++ni)
        #pragma unroll
        for (int j = 0; j < 4; ++j)
          C[(size_t)(m0 + wm + mi * 16 + rr + j) * N + (n0 + wn + ni * 16 + cc)] = acc[mi][ni][j];
  }
}

// ---------------- 256-tile 8-phase counted-vmcnt fp16 GEMM. MODE 2: QKV epilogue ----------------
template<int MODE>
__global__ __launch_bounds__(512, 2) void k_g256(const ushort* __restrict__ A, const ushort* __restrict__ Bt,
                                                 ushort* __restrict__ H, int N, int K,
                                                 ushort* __restrict__ qbuf, ushort* __restrict__ kbuf,
                                                 ushort* __restrict__ vtb,
                                                 float* __restrict__ qtb, float* __restrict__ ktb,
                                                 const float* __restrict__ cosb, const float* __restrict__ sinb) {
  __shared__ ushort sA[2][2][256 * 32];
  __shared__ ushort sB[2][2][256 * 32];
  const int t = threadIdx.x;
  const int w = t >> 6, l = t & 63;
  const int wr = w >> 2, wc = w & 3;
  const int lr = l & 15, hi4 = l >> 4;
  int bx, by;
  xcd_remap(bx, by);
  const int m0 = bx * 256, n0 = by * 256;

  auto stageA = [&](int kt, int kh, int buf) {
    #pragma unroll
    for (int ii = 0; ii < 2; ++ii) {
      int q = ii * 512 + t;
      int r = q >> 2, ci = q & 3;
      gld16(&A[(size_t)(m0 + r) * K + kt * 64 + kh * 32 + ((ci ^ ((r >> 1) & 3)) * 8)], &sA[buf][kh][q * 8]);
    }
  };
  auto stageB = [&](int kt, int kh, int buf) {
    #pragma unroll
    for (int ii = 0; ii < 2; ++ii) {
      int q = ii * 512 + t;
      int r = q >> 2, ci = q & 3;
      gld16(&Bt[(size_t)(n0 + r) * K + kt * 64 + kh * 32 + ((ci ^ ((r >> 1) & 3)) * 8)], &sB[buf][kh][q * 8]);
    }
  };

  f32x4 acc[8][4] = {};
  auto ldA = [&](int buf, int ks, int G, f16x8* fr) {
    #pragma unroll
    for (int mi = 0; mi < 4; ++mi) {
      int r = wr * 128 + (G * 4 + mi) * 16 + lr;
      fr[mi] = *(const f16x8*)&sA[buf][ks][(r * 4 + (hi4 ^ ((r >> 1) & 3))) * 8];
    }
  };
  auto ldB = [&](int buf, int ks, f16x8* fr) {
    #pragma unroll
    for (int ni = 0; ni < 4; ++ni) {
      int r = wc * 64 + ni * 16 + lr;
      fr[ni] = *(const f16x8*)&sB[buf][ks][(r * 4 + (hi4 ^ ((r >> 1) & 3))) * 8];
    }
  };
  auto mmaG = [&](int G, f16x8* a, f16x8* b) {
    __builtin_amdgcn_s_setprio(1);
    #pragma unroll
    for (int mi = 0; mi < 4; ++mi)
      #pragma unroll
      for (int ni = 0; ni < 4; ++ni)
        acc[G * 4 + mi][ni] = __builtin_amdgcn_mfma_f32_16x16x32_f16(a[mi], b[ni], acc[G * 4 + mi][ni], 0, 0, 0);
    __builtin_amdgcn_s_setprio(0);
  };

  const int NT = K >> 6;
  const int NI = NT >> 1;
  stageA(0, 0, 0); stageB(0, 0, 0); stageA(0, 1, 0); stageB(0, 1, 0);

  for (int i = 0; i < NI; ++i) {
    const int T1 = 2 * i + 1, T2 = 2 * i + 2;
    const bool last = (i == NI - 1);
    f16x8 a0[4], a1[4], b0[4], b1[4];
    asm volatile("s_waitcnt vmcnt(4)" ::: "memory");
    __builtin_amdgcn_sched_barrier(0);
    __builtin_amdgcn_s_barrier();
    ldA(0, 0, 0, a0); ldB(0, 0, b0);
    stageA(T1, 0, 1);
    mmaG(0, a0, b0);
    ldA(0, 0, 1, a1);
    stageB(T1, 0, 1);
    mmaG(1, a1, b0);
    asm volatile("s_waitcnt vmcnt(4)" ::: "memory");
    __builtin_amdgcn_sched_barrier(0);
    __builtin_amdgcn_s_barrier();
    ldA(0, 1, 0, a0); ldB(0, 1, b1);
    stageA(T1, 1, 1);
    mmaG(0, a0, b1);
    ldA(0, 1, 1, a1);
    stageB(T1, 1, 1);
    mmaG(1, a1, b1);
    asm volatile("s_waitcnt vmcnt(4)" ::: "memory");
    __builtin_amdgcn_sched_barrier(0);
    __builtin_amdgcn_s_barrier();
    ldA(1, 0, 0, a0); ldB(1, 0, b0);
    if (!last) stageA(T2, 0, 0);
    mmaG(0, a0, b0);
    ldA(1, 0, 1, a1);
    if (!last) stageB(T2, 0, 0);
    mmaG(1, a1, b0);
    if (last) { asm volatile("s_waitcnt vmcnt(0)" ::: "memory"); }
    else      { asm volatile("s_waitcnt vmcnt(4)" ::: "memory"); }
    __builtin_amdgcn_sched_barrier(0);
    __builtin_amdgcn_s_barrier();
    ldA(1, 1, 0, a0); ldB(1, 1, b1);
    if (!last) stageA(T2, 1, 0);
    mmaG(0, a0, b1);
    ldA(1, 1, 1, a1);
    if (!last) stageB(T2, 1, 0);
    mmaG(1, a1, b1);
  }

  if (MODE == 2) {
    int secBase = n0 + wc * 64;
    int sec = secBase / 768;
    int hh = (secBase - sec * 768) >> 6;
    #pragma unroll
    for (int mi = 0; mi < 8; ++mi) {
      float nrm[4];
      #pragma unroll
      for (int j = 0; j < 4; ++j) {
        float ss = 0.f;
        #pragma unroll
        for (int ni = 0; ni < 4; ++ni) ss += acc[mi][ni][j] * acc[mi][ni][j];
        #pragma unroll
        for (int m = 8; m; m >>= 1) ss += __shfl_xor(ss, m, 64);
        nrm[j] = sqrtf(fmaxf(ss + 1.f, 1e-6f));
      }
      #pragma unroll
      for (int j = 0; j < 4; ++j) {
        int m = m0 + wr * 128 + mi * 16 + hi4 * 4 + j;
        if (m < NTOK) {
          int b = m / 197, nn = m - b * 197;
          int bh = b * 12 + hh;
          if (sec == 2) {
            size_t vo = (size_t)bh * 80 * 232;
            if (lr == 0) vtb[vo + nn] = h_us(nrm[j]);
            #pragma unroll
            for (int ni = 0; ni < 4; ++ni) {
              int e = ni * 16 + lr;
              vtb[vo + (size_t)(1 + e) * 232 + nn] = h_us(acc[mi][ni][j]);
            }
          } else {
            float* tb = (sec == 0) ? qtb : ktb;
            ushort* ob = (sec == 0) ? qbuf : kbuf;
            if (lr == 0) tb[(size_t)bh * 208 + nn] = nrm[j];
            size_t rowb = ((size_t)bh * 208 + nn) * 64;
            #pragma unroll
            for (int ni = 0; ni < 4; ++ni) {
              int d = ni * 16 + lr;
              float v = acc[mi][ni][j];
              float p = __shfl_xor(v, 1);
              int j2 = d >> 1;
              float cz = cosb[nn * 32 + j2], sz = sinb[nn * 32 + j2];
              float rv = ((lr & 1) == 0) ? (v * cz - p * sz) : (p * sz + v * cz);
              ob[rowb + d] = h_us(rv);
            }
          }
        }
      }
    }
  }
}

// ---------------- build tokens -> fp16 trunk ----------------
__global__ __launch_bounds__(256) void k_build_tok(const float* __restrict__ feat, const float* __restrict__ cls,
                                                   ushort* __restrict__ tok) {
  __shared__ float red[8];
  int r = blockIdx.x;
  int b = r / 197, i = r - b * 197;
  int t = threadIdx.x;
  const float* src = (i == 0) ? cls : (feat + (size_t)(b * 196 + i - 1) * 768);
  float v0 = src[t], v1 = src[256 + t], v2 = (t < 255) ? src[512 + t] : 0.f;
  float qs = bsum(v0 * v0 + v1 * v1 + v2 * v2, red);
  ushort* tp = tok + (size_t)r * 768;
  if (t == 0) tp[0] = h_us(sqrtf(fmaxf(qs + 1.f, 1e-6f)));
  tp[1 + t] = h_us(v0); tp[257 + t] = h_us(v1); if (t < 255) tp[513 + t] = h_us(v2);
}

// ---------------- lorentz layernorm (fp16 trunk) -> fp16 (pad col 767 = 0) ----------------
__global__ __launch_bounds__(256) void k_ln(const ushort* __restrict__ tok, const float* __restrict__ g,
                                            const float* __restrict__ bb, ushort* __restrict__ out) {
  __shared__ float red[8];
  int r = blockIdx.x, t = threadIdx.x;
  const ushort* xp = tok + (size_t)r * 768;
  float v0 = us_f(xp[1 + t]), v1 = us_f(xp[257 + t]), v2 = (t < 255) ? us_f(xp[513 + t]) : 0.f;
  float s = bsum(v0 + v1 + v2, red);
  float q = bsum(v0 * v0 + v1 * v1 + v2 * v2, red);
  float mu = s * (1.f / 767.f);
  float rstd = rsqrtf(fmaxf(q * (1.f / 767.f) - mu * mu, 0.f) + 1e-6f);
  size_t o = (size_t)r * 768;
  out[o + t]       = h_us((v0 - mu) * rstd * g[t]       + bb[t]);
  out[o + 256 + t] = h_us((v1 - mu) * rstd * g[256 + t] + bb[256 + t]);
  if (t < 255)
    out[o + 512 + t] = h_us((v2 - mu) * rstd * g[512 + t] + bb[512 + t]);
  if (t == 255) out[o + 767] = 0;
}

// ---------------- MFMA attention, barrier-free: K/kt/V from L2, per-wave P in LDS ----------------
__global__ __launch_bounds__(128) void k_attn(const ushort* __restrict__ qbuf,
                                              const float* __restrict__ qtb,
                                              const ushort* __restrict__ kbuf,
                                              const float* __restrict__ ktb,
                                              const ushort* __restrict__ vtb,
                                              ushort* __restrict__ outa) {
  __shared__ ushort sP[2][16 * 248];
  int bxt = blockIdx.x, bh = blockIdx.y;
  int b = bh / 12, hd = bh - b * 12;
  int t = threadIdx.x, w = t >> 6, l = t & 63;
  int rt = bxt * 2 + w;
  if (rt >= 13) return;
  int lr = l & 15, hi4 = l >> 4;
  const ushort* qg = qbuf + (size_t)bh * 208 * 64;
  const ushort* kg = kbuf + (size_t)bh * 208 * 64;
  const ushort* vg = vtb + (size_t)bh * 80 * 232;
  const float*  ktp = ktb + (size_t)bh * 208;
  const float invs = 0.03608439182435161f;
  ushort* pw = &sP[w][0];

  int qrow = (rt * 16 + lr) * 64 + hi4 * 8;
  f16x8 q0 = *(const f16x8*)&qg[qrow];
  f16x8 q1 = *(const f16x8*)&qg[qrow + 32];
  float qt4[4];
  #pragma unroll
  for (int j = 0; j < 4; ++j) qt4[j] = qtb[(size_t)bh * 208 + rt * 16 + hi4 * 4 + j];
  f32x4 acc[13];
  #pragma unroll
  for (int nt = 0; nt < 13; ++nt) {
    int kr = (nt * 16 + lr) * 64 + hi4 * 8;
    f16x8 k0 = *(const f16x8*)&kg[kr];
    f16x8 k1 = *(const f16x8*)&kg[kr + 32];
    acc[nt] = (f32x4){0.f, 0.f, 0.f, 0.f};
    acc[nt] = __builtin_amdgcn_mfma_f32_16x16x32_f16(q0, k0, acc[nt], 0, 0, 0);
    acc[nt] = __builtin_amdgcn_mfma_f32_16x16x32_f16(q1, k1, acc[nt], 0, 0, 0);
  }
  float mx[4] = {-1e30f, -1e30f, -1e30f, -1e30f};
  #pragma unroll
  for (int nt = 0; nt < 13; ++nt) {
    int cI = nt * 16 + lr;
    float ktc = ktp[cI];
    bool valid = (cI < 197);
    #pragma unroll
    for (int j = 0; j < 4; ++j) {
      float s = (2.f + 2.f * (acc[nt][j] - qt4[j] * ktc)) * invs;
      acc[nt][j] = s;
      if (valid) mx[j] = fmaxf(mx[j], s);
    }
  }
  #pragma unroll
  for (int j = 0; j < 4; ++j)
    #pragma unroll
    for (int m = 8; m; m >>= 1) mx[j] = fmaxf(mx[j], __shfl_xor(mx[j], m, 64));
  #pragma unroll
  for (int nt = 0; nt < 14; ++nt) {
    int cI = nt * 16 + lr;
    #pragma unroll
    for (int j = 0; j < 4; ++j) {
      float p = (nt < 13 && cI < 197) ? __expf(acc[nt][j] - mx[j]) : 0.f;
      pw[(hi4 * 4 + j) * 248 + cI] = h_us(p);
    }
  }
  f32x4 accO[5];
  #pragma unroll
  for (int et = 0; et < 5; ++et) accO[et] = (f32x4){0.f, 0.f, 0.f, 0.f};
  #pragma unroll
  for (int ks = 0; ks < 7; ++ks) {
    f16x8 pa = *(const f16x8*)&pw[lr * 248 + ks * 32 + hi4 * 8];
    #pragma unroll
    for (int et = 0; et < 5; ++et) {
      int er = et * 16 + lr;
      f16x8 bv = *(const f16x8*)&vg[(er > 64 ? 64 : er) * 232 + ks * 32 + hi4 * 8];
      accO[et] = __builtin_amdgcn_mfma_f32_16x16x32_f16(pa, bv, accO[et], 0, 0, 0);
    }
  }
  float ssq[4] = {0.f, 0.f, 0.f, 0.f};
  #pragma unroll
  for (int et = 0; et < 4; ++et)
    #pragma unroll
    for (int j = 0; j < 4; ++j) ssq[j] += accO[et][j] * accO[et][j];
  if (lr == 0) {
    #pragma unroll
    for (int j = 0; j < 4; ++j) ssq[j] += accO[4][j] * accO[4][j];
  }
  #pragma unroll
  for (int j = 0; j < 4; ++j)
    #pragma unroll
    for (int m = 8; m; m >>= 1) ssq[j] += __shfl_xor(ssq[j], m, 64);
  float rf4[4];
  #pragma unroll
  for (int j = 0; j < 4; ++j) {
    float o0 = __shfl(accO[0][j], (l & 48));
    rf4[j] = rsqrtf(fmaxf(2.f * o0 * o0 - ssq[j], 1e-6f));
  }
  #pragma unroll
  for (int et = 0; et < 5; ++et) {
    int e = et * 16 + lr;
    if (e == 0 || e >= 65) continue;
    #pragma unroll
    for (int j = 0; j < 4; ++j) {
      int n = rt * 16 + hi4 * 4 + j;
      if (n < 197)
        outa[((size_t)(b * 197 + n)) * 768 + hd * 64 + (e - 1)] = h_us(accO[et][j] * rf4[j]);
    }
  }
}

// ---------------- fused lresnet + LN: wave-per-row, barrier-free ----------------
template<int FIN>
__global__ __launch_bounds__(256) void k_resnet_ln(ushort* __restrict__ tok, const ushort* __restrict__ s,
                                                   const float* __restrict__ wyp, int l,
                                                   const float* __restrict__ g, const float* __restrict__ bb,
                                                   ushort* __restrict__ out16, float* __restrict__ out32) {
  int w = threadIdx.x >> 6, lane = threadIdx.x & 63;
  int r = blockIdx.x * 4 + w;         // NTOK = 1576*4 exactly
  float wv = wyp[l];
  const ushort* sp = s + (size_t)r * 768;
  ushort* tp = tok + (size_t)r * 768;
  float sv[12], zv[12];
  float qs = 0.f;
  #pragma unroll
  for (int i = 0; i < 12; ++i) {
    int j = lane + 64 * i;
    float si = (j < 767) ? us_f(sp[j]) : 0.f;
    sv[i] = si; qs += si * si;
  }
  #pragma unroll
  for (int m = 32; m; m >>= 1) qs += __shfl_xor(qs, m, 64);
  float at = sqrtf(fmaxf(qs + 1.f, 1e-6f));
  float zs = 0.f;
  #pragma unroll
  for (int i = 0; i < 12; ++i) {
    int j = lane + 64 * i;
    float zi = (j < 767) ? (us_f(tp[1 + j]) + wv * sv[i]) : 0.f;
    zv[i] = zi; zs += zi * zi;
  }
  #pragma unroll
  for (int m = 32; m; m >>= 1) zs += __shfl_xor(zs, m, 64);
  float zt = us_f(tp[0]) + wv * at;
  float rf = rsqrtf(fmaxf(zt * zt - zs, 1e-6f));
  float sm = 0.f, sq = 0.f;
  #pragma unroll
  for (int i = 0; i < 12; ++i) {
    float ni = zv[i] * rf;
    zv[i] = ni;
    int j = lane + 64 * i;
    if (j < 767) tp[1 + j] = h_us(ni);
    sm += ni; sq += ni * ni;
  }
  if (lane == 0) tp[0] = h_us(zt * rf);
  #pragma unroll
  for (int m = 32; m; m >>= 1) { sm += __shfl_xor(sm, m, 64); sq += __shfl_xor(sq, m, 64); }
  float mu = sm * (1.f / 767.f);
  float rstd = rsqrtf(fmaxf(sq * (1.f / 767.f) - mu * mu, 0.f) + 1e-6f);
  if (FIN) {
    float yv[12];
    float qq = 0.f;
    #pragma unroll
    for (int i = 0; i < 12; ++i) {
      int j = lane + 64 * i;
      float y = (j < 767) ? ((zv[i] - mu) * rstd * g[j] + bb[j]) : 0.f;
      yv[i] = y; qq += y * y;
    }
    #pragma unroll
    for (int m = 32; m; m >>= 1) qq += __shfl_xor(qq, m, 64);
    float* op = out32 + (size_t)r * 768;
    #pragma unroll
    for (int i = 0; i < 12; ++i) {
      int j = lane + 64 * i;
      if (j < 767) op[1 + j] = yv[i];
    }
    if (lane == 0) op[0] = sqrtf(fmaxf(qq + 1.f, 1e-6f));
  } else {
    size_t o = (size_t)r * 768;
    #pragma unroll
    for (int i = 0; i < 12; ++i) {
      int j = lane + 64 * i;
      if (j < 767) out16[o + j] = h_us((zv[i] - mu) * rstd * g[j] + bb[j]);
      else if (j == 767) out16[o + 767] = 0;
    }
  }
}

extern "C" void kernel_launch(void* const* d_in, const int* in_sizes, int n_in,
                              void* d_out, int out_size, void* d_ws, size_t ws_size,
                              hipStream_t stream) {
  const float* x     = (const float*)d_in[0];
  const float* cls_s = (const float*)d_in[1];
  const float* Wp    = (const float*)d_in[2];
  const float* ln1g  = (const float*)d_in[3];
  const float* ln1b  = (const float*)d_in[4];
  const float* Wq    = (const float*)d_in[5];
  const float* Wk    = (const float*)d_in[6];
  const float* Wv    = (const float*)d_in[7];
  const float* Wo    = (const float*)d_in[8];
  const float* ln2g  = (const float*)d_in[9];
  const float* ln2b  = (const float*)d_in[10];
  const float* W1    = (const float*)d_in[11];
  const float* W2    = (const float*)d_in[12];
  const float* W3    = (const float*)d_in[13];
  const float* wy1   = (const float*)d_in[14];
  const float* wy2   = (const float*)d_in[15];
  const float* lnfg  = (const float*)d_in[16];
  const float* lnfb  = (const float*)d_in[17];

  if (ws_size < B_END) return;

  char* ws = (char*)d_ws;
  float*  cosb   = (float*)(ws + B_COS);
  float*  sinb   = (float*)(ws + B_SIN);
  ushort* wpt    = (ushort*)(ws + B_WPT);
  ushort* apatch = (ushort*)(ws + B_APATCH);
  ushort* wqkvt  = (ushort*)(ws + B_WQKVT);
  ushort* wot    = (ushort*)(ws + B_WOT);
  ushort* w12t   = (ushort*)(ws + B_W12T);
  ushort* w3t    = (ushort*)(ws + B_W3T);
  ushort* tok    = (ushort*)(ws + B_TOK);
  ushort* acta   = (ushort*)(ws + B_ACTA);
  ushort* actb   = (ushort*)(ws + B_ACTB);
  float*  gout   = (float*)(ws + B_GOUT);
  ushort* gouth  = (ushort*)(ws + B_GOUT);
  ushort* qbuf   = (ushort*)(ws + B_QB);
  ushort* kbuf   = (ushort*)(ws + B_KB);
  ushort* vtb    = (ushort*)(ws + B_VT);
  float*  qtb    = (float*)(ws + B_QTB);
  float*  ktb    = (float*)(ws + B_KTB);

  // only V pads must be zero (P=0 x garbage would still contribute via PV MFMA).
  hipMemsetAsync(vtb, 0, VELE * 2, stream);

  k_rope_tab<<<25, 256, 0, stream>>>(cosb, sinb);
  k_tpose<<<32 * 24, 256, 0, stream>>>(Wp, wpt, 1024, 767, 32, 1024);
  k_im2col<<<CONVM, 256, 0, stream>>>(x, apatch);
  k_wprep12<<<3456 * NLAYER, 256, 0, stream>>>(Wq, Wk, Wv, Wo, W1, W2, W3, wqkvt, wot, w12t, w3t);
  k_gemmh<0><<<dim3(49, 6), 256, 0, stream>>>(apatch, wpt, gout, nullptr, 768, 1024);
  k_build_tok<<<NTOK, 256, 0, stream>>>(gout, cls_s, tok);
  k_ln<<<NTOK, 256, 0, stream>>>(tok, ln1g, ln1b, acta);

  for (int l = 0; l < NLAYER; ++l) {
    const ushort* wq_l  = wqkvt + (size_t)l * WS_QKV;
    const ushort* wo_l  = wot   + (size_t)l * WS_WO;
    const ushort* w12_l = w12t  + (size_t)l * WS_W12;
    const ushort* w3_l  = w3t   + (size_t)l * WS_W3;

    k_g256<2><<<dim3(25, 9), 512, 0, stream>>>(acta, wq_l, nullptr, 2304, 768,
                                               qbuf, kbuf, vtb, qtb, ktb, cosb, sinb);
    k_attn<<<dim3(7, 384), 128, 0, stream>>>(qbuf, qtb, kbuf, ktb, vtb, acta);
    k_gemmh<3><<<dim3(50, 6), 256, 0, stream>>>(acta, wo_l, nullptr, gouth, 768, 768);
    k_resnet_ln<0><<<1576, 256, 0, stream>>>(tok, gouth, wy1, l,
                                             ln2g + (size_t)l * 767, ln2b + (size_t)l * 767, acta, nullptr);

    k_gemmh<1><<<dim3(50, 32), 256, 0, stream>>>(acta, w12_l, nullptr, actb, 4096, 768);
    k_gemmh<3><<<dim3(50, 6), 256, 0, stream>>>(actb, w3_l, nullptr, gouth, 768, 2048);
    if (l < NLAYER - 1)
      k_resnet_ln<0><<<1576, 256, 0, stream>>>(tok, gouth, wy2, l,
                                               ln1g + (size_t)(l + 1) * 767, ln1b + (size_t)(l + 1) * 767,
                                               acta, nullptr);
    else
      k_resnet_ln<1><<<1576, 256, 0, stream>>>(tok, gouth, wy2, l, lnfg, lnfb, nullptr, (float*)d_out);
  }
}

// Round 17
// 2940.910 us; speedup vs baseline: 1.4345x; 1.0653x over previous
//
#include <hip/hip_runtime.h>
#include <hip/hip_bf16.h>

typedef __attribute__((ext_vector_type(8))) short short8;
typedef __attribute__((ext_vector_type(4))) float f32x4;
typedef _Float16 f16x8 __attribute__((ext_vector_type(8)));

#define NLAYER 12
#define NTOK   6304
#define MPAD   6400
#define CONVM  6272

#define QELE     ((size_t)384*208*64)
#define VELE     ((size_t)384*80*232)

// per-layer weight strides (elements)
#define WS_QKV ((size_t)2304*768)
#define WS_WO  ((size_t)768*768)
#define WS_W12 ((size_t)4096*768)
#define WS_W3  ((size_t)768*2048)

static constexpr size_t AL(size_t x){ return (x + 511) & ~(size_t)511; }
static constexpr size_t B_COS    = 0;
static constexpr size_t B_SIN    = AL(B_COS    + (size_t)197*32*4);
static constexpr size_t B_WPT    = AL(B_SIN    + (size_t)197*32*4);
static constexpr size_t B_APATCH = AL(B_WPT    + (size_t)768*1024*2);
static constexpr size_t B_WQKVT  = AL(B_APATCH + (size_t)CONVM*1024*2);
static constexpr size_t B_WOT    = AL(B_WQKVT  + WS_QKV*NLAYER*2);
static constexpr size_t B_W12T   = AL(B_WOT    + WS_WO*NLAYER*2);
static constexpr size_t B_W3T    = AL(B_W12T   + WS_W12*NLAYER*2);
static constexpr size_t B_TOK    = AL(B_W3T    + WS_W3*NLAYER*2);
static constexpr size_t B_ACTA   = AL(B_TOK    + (size_t)NTOK*768*2);
static constexpr size_t B_ACTB   = AL(B_ACTA   + (size_t)MPAD*768*2);
static constexpr size_t B_GOUT   = AL(B_ACTB   + (size_t)MPAD*2048*2);
static constexpr size_t B_QB     = AL(B_GOUT   + (size_t)MPAD*768*4);
static constexpr size_t B_KB     = AL(B_QB     + QELE*2);
static constexpr size_t B_VT     = AL(B_KB     + QELE*2);
static constexpr size_t B_QTB    = AL(B_VT     + VELE*2);
static constexpr size_t B_KTB    = AL(B_QTB    + (size_t)384*208*4);
static constexpr size_t B_END    = AL(B_KTB    + (size_t)384*208*4);

typedef __attribute__((address_space(1))) unsigned int gu32;
typedef __attribute__((address_space(3))) unsigned int lu32;
__device__ __forceinline__ void gld16(const void* g, void* l) {
  __builtin_amdgcn_global_load_lds((const gu32*)g, (lu32*)l, 16, 0, 0);
}

// ---------------- helpers ----------------
__device__ __forceinline__ float bsum(float v, float* red) {
  #pragma unroll
  for (int m = 32; m; m >>= 1) v += __shfl_xor(v, m, 64);
  __syncthreads();
  if ((threadIdx.x & 63) == 0) red[threadIdx.x >> 6] = v;
  __syncthreads();
  return red[0] + red[1] + red[2] + red[3];
}

__device__ __forceinline__ ushort h_us(float v) {
  _Float16 h = (_Float16)v;
  return *(ushort*)&h;
}
__device__ __forceinline__ float us_f(ushort u) {
  return (float)*(const _Float16*)&u;
}

// bijective XCD-chunked remap (m204)
__device__ __forceinline__ void xcd_remap(int& bx, int& by) {
  int gx = gridDim.x, gy = gridDim.y;
  int nwg = gx * gy;
  int orig = blockIdx.y * gx + blockIdx.x;
  int q = nwg >> 3, r = nwg & 7;
  int xcd = orig & 7, loc = orig >> 3;
  int wg = (xcd < r ? xcd * (q + 1) : r * (q + 1) + (xcd - r) * q) + loc;
  bx = wg / gy;
  by = wg % gy;
}

// ---------------- RoPE tables ----------------
__global__ void k_rope_tab(float* __restrict__ cosb, float* __restrict__ sinb) {
  int idx = blockIdx.x * 256 + threadIdx.x;
  if (idx >= 197 * 32) return;
  int p = idx >> 5, j = idx & 31;
  float cv, sv;
  if (p == 0) { cv = 1.f; sv = 0.f; }
  else {
    int pp = p - 1;
    int iy = pp / 14, ix = pp - iy * 14;
    int pos = (j < 16) ? iy : ix;
    int f   = (j < 16) ? j  : j - 16;
    float inv = powf(100.f, -(float)f / 16.f);
    float a = (float)pos * inv;
    cv = cosf(a); sv = sinf(a);
  }
  cosb[idx] = cv; sinb[idx] = sv;
}

// ---------------- 32x32 LDS-tiled transpose (prologue Wp only) ----------------
__device__ __forceinline__ void tpose_tile(const float* __restrict__ src, ushort* __restrict__ dst,
                                           int K, int N, int ldd, int imode, int tk, int tn) {
  __shared__ float ts[32][33];
  int t = threadIdx.x;
  int rr = t >> 3, c4 = (t & 7) * 4;
  int k0 = tk * 32, n0 = tn * 32;
  int k = k0 + rr, nb = n0 + c4;
  const float* sp = src + (size_t)k * N + nb;
  if (k < K && nb + 3 < N && (((size_t)sp & 15) == 0)) {
    float4 v = *(const float4*)sp;
    ts[rr][c4] = v.x; ts[rr][c4 + 1] = v.y; ts[rr][c4 + 2] = v.z; ts[rr][c4 + 3] = v.w;
  } else {
    #pragma unroll
    for (int e = 0; e < 4; ++e) {
      int n = nb + e;
      ts[rr][c4 + e] = (k < K && n < N) ? src[(size_t)k * N + n] : 0.f;
    }
  }
  __syncthreads();
  int c = n0 + rr;
  int drow = (imode == 0) ? c : (16 * (c >> 3) + (c & 7) + (imode == 2 ? 8 : 0));
  ushort4 o;
  #pragma unroll
  for (int e = 0; e < 4; ++e) {
    _Float16 hv = (_Float16)ts[c4 + e][rr];
    ((ushort*)&o)[e] = *(ushort*)&hv;
  }
  *(ushort4*)&dst[(size_t)drow * ldd + k0 + c4] = o;
}

__global__ __launch_bounds__(256) void k_tpose(const float* __restrict__ src, ushort* __restrict__ dst,
                                               int K, int N, int ktiles, int ldd) {
  int tk = blockIdx.x % ktiles, tn = blockIdx.x / ktiles;
  tpose_tile(src, dst, K, N, ldd, 0, tk, tn);
}

// ---------------- 64x32 tile: float4 reads, 16B short8 writes (128B/row) ----------------
__device__ __forceinline__ void tpose_tile64(const float* __restrict__ src, ushort* __restrict__ dst,
                                             int K, int N, int ldd, int imode, int tk, int tn) {
  __shared__ float ts[64][33];
  int t = threadIdx.x;
  int row = t >> 3;            // 0..31
  int c4 = (t & 7) * 4;        // 0..28
  int k0 = tk * 64, n0 = tn * 32;
  #pragma unroll
  for (int ph = 0; ph < 2; ++ph) {
    int kr = row + ph * 32;
    int k = k0 + kr;
    int nb = n0 + c4;
    const float* sp = src + (size_t)k * N + nb;
    if (k < K && nb + 3 < N && (((size_t)sp & 15) == 0)) {
      float4 v = *(const float4*)sp;
      ts[kr][c4] = v.x; ts[kr][c4 + 1] = v.y; ts[kr][c4 + 2] = v.z; ts[kr][c4 + 3] = v.w;
    } else {
      #pragma unroll
      for (int e = 0; e < 4; ++e) {
        int n = nb + e;
        ts[kr][c4 + e] = (k < K && n < N) ? src[(size_t)k * N + n] : 0.f;
      }
    }
  }
  __syncthreads();
  int rr2 = t >> 3;            // output row within n-tile
  int kc8 = (t & 7) * 8;
  int c = n0 + rr2;
  int drow = (imode == 0) ? c : (16 * (c >> 3) + (c & 7) + (imode == 2 ? 8 : 0));
  short8 o8;
  #pragma unroll
  for (int e = 0; e < 8; ++e) {
    _Float16 hv = (_Float16)ts[kc8 + e][rr2];
    o8[e] = *(short*)&hv;
  }
  *(short8*)&dst[(size_t)drow * ldd + k0 + kc8] = o8;
}

// all 7 weight transposes x all 12 layers, 3456 tiles/layer
__global__ __launch_bounds__(256) void k_wprep12(const float* __restrict__ Wq, const float* __restrict__ Wk,
                                                 const float* __restrict__ Wv, const float* __restrict__ Wo,
                                                 const float* __restrict__ W1, const float* __restrict__ W2,
                                                 const float* __restrict__ W3,
                                                 ushort* __restrict__ wqkvt, ushort* __restrict__ wot,
                                                 ushort* __restrict__ w12t, ushort* __restrict__ w3t) {
  int gt = blockIdx.x;
  int l = gt / 3456;
  int tile = gt - l * 3456;
  const float* q  = Wq + (size_t)l * 767 * 768;
  const float* kk = Wk + (size_t)l * 767 * 768;
  const float* v  = Wv + (size_t)l * 767 * 768;
  const float* o  = Wo + (size_t)l * 768 * 767;
  const float* w1 = W1 + (size_t)l * 767 * 2048;
  const float* w2 = W2 + (size_t)l * 767 * 2048;
  const float* w3 = W3 + (size_t)l * 2048 * 767;
  ushort* dqkv = wqkvt + (size_t)l * WS_QKV;
  ushort* dwo  = wot   + (size_t)l * WS_WO;
  ushort* dw12 = w12t  + (size_t)l * WS_W12;
  ushort* dw3  = w3t   + (size_t)l * WS_W3;
  const float* src; ushort* dst;
  int K, N, ktiles, ldd, imode = 0, tl;
  if (tile < 864) {
    int jb = tile / 288; tl = tile % 288;
    ktiles = 12; ldd = 768; K = 767; N = 768;
    src = (jb == 0) ? q : (jb == 1) ? kk : v;
    dst = dqkv + (size_t)jb * 768 * 768;
  } else if (tile < 1152) {
    tl = tile - 864;
    ktiles = 12; ldd = 768; K = 768; N = 767; src = o; dst = dwo;
  } else if (tile < 2688) {
    int jb = (tile - 1152) / 768; tl = (tile - 1152) % 768;
    ktiles = 12; ldd = 768; K = 767; N = 2048; dst = dw12;
    src = jb ? w2 : w1; imode = jb ? 2 : 1;
  } else {
    tl = tile - 2688; ktiles = 32; ldd = 2048; K = 2048; N = 767; src = w3; dst = dw3;
  }
  int tk = tl % ktiles, tn = tl / ktiles;
  tpose_tile64(src, dst, K, N, ldd, imode, tk, tn);
}

// ---------------- im2col with Lorentz time channel, fp16 ----------------
__global__ __launch_bounds__(256) void k_im2col(const float* __restrict__ x, ushort* __restrict__ ap) {
  int r = blockIdx.x;
  int b = r / 196, pi = r - b * 196;
  int py = pi / 14, px = pi - py * 14;
  int t = threadIdx.x;
  int ph = t >> 4, pw = t & 15;
  int iy = py * 16 + ph, ix = px * 16 + pw;
  size_t base = ((size_t)b * 3 * 224 + iy) * 224 + ix;
  float x0 = x[base];
  float x1 = x[base + 224 * 224];
  float x2 = x[base + 2 * 224 * 224];
  float tv = sqrtf(fmaxf(x0 * x0 + x1 * x1 + x2 * x2 + 1.f, 1e-6f));
  size_t o = (size_t)r * 1024 + t * 4;
  ap[o] = h_us(tv); ap[o + 1] = h_us(x0); ap[o + 2] = h_us(x1); ap[o + 3] = h_us(x2);
}

// ---------------- 128xBN fp16 GEMM (single-buffer 2-barrier, proven inner loop). BN = NSUB*32. ----------------
// Each of the 2 N-waves owns NSUB 16-col fragments (wn stride = 16*NSUB).
// MODE 0: f32 C; 1: fused silu -> fp16 H (NSUB=4 only); 3: fp16 H.
template<int MODE, int NSUB>
__global__ __launch_bounds__(256) void k_gemmh(const ushort* __restrict__ A, const ushort* __restrict__ Bt,
                                               float* __restrict__ C, ushort* __restrict__ H,
                                               int N, int K) {
  __shared__ ushort sA[128 * 64];
  __shared__ ushort sB[NSUB * 32 * 64];
  int bx, by;
  xcd_remap(bx, by);
  int m0 = bx * 128, n0 = by * (NSUB * 32);
  int t = threadIdx.x;
  int w = t >> 6, l = t & 63;
  int wm = (w >> 1) * 64, wn = (w & 1) * (NSUB * 16);
  int lr = l & 15, hi = l >> 4;
  f32x4 acc[4][NSUB] = {};
  for (int k0 = 0; k0 < K; k0 += 64) {
    #pragma unroll
    for (int i = 0; i < 4; ++i) {
      int fl = i * 256 + t;
      int r = fl >> 3, c = fl & 7;
      int cs = c ^ (r & 7);
      gld16(&A[(size_t)(m0 + r) * K + k0 + cs * 8], &sA[fl * 8]);
    }
    #pragma unroll
    for (int i = 0; i < NSUB; ++i) {
      int fl = i * 256 + t;
      int r = fl >> 3, c = fl & 7;
      int cs = c ^ (r & 7);
      gld16(&Bt[(size_t)(n0 + r) * K + k0 + cs * 8], &sB[fl * 8]);
    }
    __syncthreads();
    f16x8 af[4][2], bfr[NSUB][2];
    #pragma unroll
    for (int q = 0; q < 4; ++q) {
      int ra = wm + q * 16 + lr;
      #pragma unroll
      for (int h = 0; h < 2; ++h)
        af[q][h] = *(const f16x8*)&sA[ra * 64 + ((h * 4 + hi) ^ (ra & 7)) * 8];
    }
    #pragma unroll
    for (int q = 0; q < NSUB; ++q) {
      int rb = wn + q * 16 + lr;
      #pragma unroll
      for (int h = 0; h < 2; ++h)
        bfr[q][h] = *(const f16x8*)&sB[rb * 64 + ((h * 4 + hi) ^ (rb & 7)) * 8];
    }
    #pragma unroll
    for (int mi = 0; mi < 4; ++mi)
      #pragma unroll
      for (int ni = 0; ni < NSUB; ++ni) {
        acc[mi][ni] = __builtin_amdgcn_mfma_f32_16x16x32_f16(af[mi][0], bfr[ni][0], acc[mi][ni], 0, 0, 0);
        acc[mi][ni] = __builtin_amdgcn_mfma_f32_16x16x32_f16(af[mi][1], bfr[ni][1], acc[mi][ni], 0, 0, 0);
      }
    __syncthreads();
  }
  int rr = hi * 4, cc = lr;
  if (MODE == 1) {
    #pragma unroll
    for (int mi = 0; mi < 4; ++mi)
      #pragma unroll
      for (int ni = 0; ni < NSUB; ++ni) {
        int g = (n0 + wn + ni * 16) >> 4;
        #pragma unroll
        for (int j = 0; j < 4; ++j) {
          float v = acc[mi][ni][j];
          float p = __shfl_xor(v, 8);
          float u1 = (cc < 8) ? v : p;
          float u2 = (cc < 8) ? p : v;
          float hv = u1 / (1.f + __expf(-u1)) * u2;
          if (cc < 8)
            H[(size_t)(m0 + wm + mi * 16 + rr + j) * 2048 + g * 8 + cc] = h_us(hv);
        }
      }
  } else if (MODE == 3) {
    #pragma unroll
    for (int mi = 0; mi < 4; ++mi)
      #pragma unroll
      for (int ni = 0; ni < NSUB; ++ni)
        #pragma unroll
        for (int j = 0; j < 4; ++j)
          H[(size_t)(m0 + wm + mi * 16 + rr + j) * N + (n0 + wn + ni * 16 + cc)] = h_us(acc[mi][ni][j]);
  } else {
    #pragma unroll
    for (int mi = 0; mi < 4; ++mi)
      #pragma unroll
      for (int ni = 0; ni < NSUB; ++ni)
        #pragma unroll
        for (int j = 0; j < 4; ++j)
          C[(size_t)(m0 + wm + mi * 16 + rr + j) * N + (n0 + wn + ni * 16 + cc)] = acc[mi][ni][j];
  }
}

// ---------------- 256-tile 8-phase counted-vmcnt fp16 GEMM. MODE 2: QKV epilogue ----------------
template<int MODE>
__global__ __launch_bounds__(512, 2) void k_g256(const ushort* __restrict__ A, const ushort* __restrict__ Bt,
                                                 ushort* __restrict__ H, int N, int K,
                                                 ushort* __restrict__ qbuf, ushort* __restrict__ kbuf,
                                                 ushort* __restrict__ vtb,
                                                 float* __restrict__ qtb, float* __restrict__ ktb,
                                                 const float* __restrict__ cosb, const float* __restrict__ sinb) {
  __shared__ ushort sA[2][2][256 * 32];
  __shared__ ushort sB[2][2][256 * 32];
  const int t = threadIdx.x;
  const int w = t >> 6, l = t & 63;
  const int wr = w >> 2, wc = w & 3;
  const int lr = l & 15, hi4 = l >> 4;
  int bx, by;
  xcd_remap(bx, by);
  const int m0 = bx * 256, n0 = by * 256;

  auto stageA = [&](int kt, int kh, int buf) {
    #pragma unroll
    for (int ii = 0; ii < 2; ++ii) {
      int q = ii * 512 + t;
      int r = q >> 2, ci = q & 3;
      gld16(&A[(size_t)(m0 + r) * K + kt * 64 + kh * 32 + ((ci ^ ((r >> 1) & 3)) * 8)], &sA[buf][kh][q * 8]);
    }
  };
  auto stageB = [&](int kt, int kh, int buf) {
    #pragma unroll
    for (int ii = 0; ii < 2; ++ii) {
      int q = ii * 512 + t;
      int r = q >> 2, ci = q & 3;
      gld16(&Bt[(size_t)(n0 + r) * K + kt * 64 + kh * 32 + ((ci ^ ((r >> 1) & 3)) * 8)], &sB[buf][kh][q * 8]);
    }
  };

  f32x4 acc[8][4] = {};
  auto ldA = [&](int buf, int ks, int G, f16x8* fr) {
    #pragma unroll
    for (int mi = 0; mi < 4; ++mi) {
      int r = wr * 128 + (G * 4 + mi) * 16 + lr;
      fr[mi] = *(const f16x8*)&sA[buf][ks][(r * 4 + (hi4 ^ ((r >> 1) & 3))) * 8];
    }
  };
  auto ldB = [&](int buf, int ks, f16x8* fr) {
    #pragma unroll
    for (int ni = 0; ni < 4; ++ni) {
      int r = wc * 64 + ni * 16 + lr;
      fr[ni] = *(const f16x8*)&sB[buf][ks][(r * 4 + (hi4 ^ ((r >> 1) & 3))) * 8];
    }
  };
  auto mmaG = [&](int G, f16x8* a, f16x8* b) {
    __builtin_amdgcn_s_setprio(1);
    #pragma unroll
    for (int mi = 0; mi < 4; ++mi)
      #pragma unroll
      for (int ni = 0; ni < 4; ++ni)
        acc[G * 4 + mi][ni] = __builtin_amdgcn_mfma_f32_16x16x32_f16(a[mi], b[ni], acc[G * 4 + mi][ni], 0, 0, 0);
    __builtin_amdgcn_s_setprio(0);
  };

  const int NT = K >> 6;
  const int NI = NT >> 1;
  stageA(0, 0, 0); stageB(0, 0, 0); stageA(0, 1, 0); stageB(0, 1, 0);

  for (int i = 0; i < NI; ++i) {
    const int T1 = 2 * i + 1, T2 = 2 * i + 2;
    const bool last = (i == NI - 1);
    f16x8 a0[4], a1[4], b0[4], b1[4];
    asm volatile("s_waitcnt vmcnt(4)" ::: "memory");
    __builtin_amdgcn_sched_barrier(0);
    __builtin_amdgcn_s_barrier();
    ldA(0, 0, 0, a0); ldB(0, 0, b0);
    stageA(T1, 0, 1);
    mmaG(0, a0, b0);
    ldA(0, 0, 1, a1);
    stageB(T1, 0, 1);
    mmaG(1, a1, b0);
    asm volatile("s_waitcnt vmcnt(4)" ::: "memory");
    __builtin_amdgcn_sched_barrier(0);
    __builtin_amdgcn_s_barrier();
    ldA(0, 1, 0, a0); ldB(0, 1, b1);
    stageA(T1, 1, 1);
    mmaG(0, a0, b1);
    ldA(0, 1, 1, a1);
    stageB(T1, 1, 1);
    mmaG(1, a1, b1);
    asm volatile("s_waitcnt vmcnt(4)" ::: "memory");
    __builtin_amdgcn_sched_barrier(0);
    __builtin_amdgcn_s_barrier();
    ldA(1, 0, 0, a0); ldB(1, 0, b0);
    if (!last) stageA(T2, 0, 0);
    mmaG(0, a0, b0);
    ldA(1, 0, 1, a1);
    if (!last) stageB(T2, 0, 0);
    mmaG(1, a1, b0);
    if (last) { asm volatile("s_waitcnt vmcnt(0)" ::: "memory"); }
    else      { asm volatile("s_waitcnt vmcnt(4)" ::: "memory"); }
    __builtin_amdgcn_sched_barrier(0);
    __builtin_amdgcn_s_barrier();
    ldA(1, 1, 0, a0); ldB(1, 1, b1);
    if (!last) stageA(T2, 1, 0);
    mmaG(0, a0, b1);
    ldA(1, 1, 1, a1);
    if (!last) stageB(T2, 1, 0);
    mmaG(1, a1, b1);
  }

  if (MODE == 2) {
    int secBase = n0 + wc * 64;
    int sec = secBase / 768;
    int hh = (secBase - sec * 768) >> 6;
    #pragma unroll
    for (int mi = 0; mi < 8; ++mi) {
      float nrm[4];
      #pragma unroll
      for (int j = 0; j < 4; ++j) {
        float ss = 0.f;
        #pragma unroll
        for (int ni = 0; ni < 4; ++ni) ss += acc[mi][ni][j] * acc[mi][ni][j];
        #pragma unroll
        for (int m = 8; m; m >>= 1) ss += __shfl_xor(ss, m, 64);
        nrm[j] = sqrtf(fmaxf(ss + 1.f, 1e-6f));
      }
      #pragma unroll
      for (int j = 0; j < 4; ++j) {
        int m = m0 + wr * 128 + mi * 16 + hi4 * 4 + j;
        if (m < NTOK) {
          int b = m / 197, nn = m - b * 197;
          int bh = b * 12 + hh;
          if (sec == 2) {
            size_t vo = (size_t)bh * 80 * 232;
            if (lr == 0) vtb[vo + nn] = h_us(nrm[j]);
            #pragma unroll
            for (int ni = 0; ni < 4; ++ni) {
              int e = ni * 16 + lr;
              vtb[vo + (size_t)(1 + e) * 232 + nn] = h_us(acc[mi][ni][j]);
            }
          } else {
            float* tb = (sec == 0) ? qtb : ktb;
            ushort* ob = (sec == 0) ? qbuf : kbuf;
            if (lr == 0) tb[(size_t)bh * 208 + nn] = nrm[j];
            size_t rowb = ((size_t)bh * 208 + nn) * 64;
            #pragma unroll
            for (int ni = 0; ni < 4; ++ni) {
              int d = ni * 16 + lr;
              float v = acc[mi][ni][j];
              float p = __shfl_xor(v, 1);
              int j2 = d >> 1;
              float cz = cosb[nn * 32 + j2], sz = sinb[nn * 32 + j2];
              float rv = ((lr & 1) == 0) ? (v * cz - p * sz) : (p * sz + v * cz);
              ob[rowb + d] = h_us(rv);
            }
          }
        }
      }
    }
  }
}

// ---------------- build tokens -> fp16 trunk ----------------
__global__ __launch_bounds__(256) void k_build_tok(const float* __restrict__ feat, const float* __restrict__ cls,
                                                   ushort* __restrict__ tok) {
  __shared__ float red[8];
  int r = blockIdx.x;
  int b = r / 197, i = r - b * 197;
  int t = threadIdx.x;
  const float* src = (i == 0) ? cls : (feat + (size_t)(b * 196 + i - 1) * 768);
  float v0 = src[t], v1 = src[256 + t], v2 = (t < 255) ? src[512 + t] : 0.f;
  float qs = bsum(v0 * v0 + v1 * v1 + v2 * v2, red);
  ushort* tp = tok + (size_t)r * 768;
  if (t == 0) tp[0] = h_us(sqrtf(fmaxf(qs + 1.f, 1e-6f)));
  tp[1 + t] = h_us(v0); tp[257 + t] = h_us(v1); if (t < 255) tp[513 + t] = h_us(v2);
}

// ---------------- lorentz layernorm (fp16 trunk) -> fp16 (pad col 767 = 0) ----------------
__global__ __launch_bounds__(256) void k_ln(const ushort* __restrict__ tok, const float* __restrict__ g,
                                            const float* __restrict__ bb, ushort* __restrict__ out) {
  __shared__ float red[8];
  int r = blockIdx.x, t = threadIdx.x;
  const ushort* xp = tok + (size_t)r * 768;
  float v0 = us_f(xp[1 + t]), v1 = us_f(xp[257 + t]), v2 = (t < 255) ? us_f(xp[513 + t]) : 0.f;
  float s = bsum(v0 + v1 + v2, red);
  float q = bsum(v0 * v0 + v1 * v1 + v2 * v2, red);
  float mu = s * (1.f / 767.f);
  float rstd = rsqrtf(fmaxf(q * (1.f / 767.f) - mu * mu, 0.f) + 1e-6f);
  size_t o = (size_t)r * 768;
  out[o + t]       = h_us((v0 - mu) * rstd * g[t]       + bb[t]);
  out[o + 256 + t] = h_us((v1 - mu) * rstd * g[256 + t] + bb[256 + t]);
  if (t < 255)
    out[o + 512 + t] = h_us((v2 - mu) * rstd * g[512 + t] + bb[512 + t]);
  if (t == 255) out[o + 767] = 0;
}

// ---------------- MFMA attention, barrier-free: K/kt/V from L2, per-wave P in LDS ----------------
__global__ __launch_bounds__(128) void k_attn(const ushort* __restrict__ qbuf,
                                              const float* __restrict__ qtb,
                                              const ushort* __restrict__ kbuf,
                                              const float* __restrict__ ktb,
                                              const ushort* __restrict__ vtb,
                                              ushort* __restrict__ outa) {
  __shared__ ushort sP[2][16 * 248];
  int bxt = blockIdx.x, bh = blockIdx.y;
  int b = bh / 12, hd = bh - b * 12;
  int t = threadIdx.x, w = t >> 6, l = t & 63;
  int rt = bxt * 2 + w;
  if (rt >= 13) return;
  int lr = l & 15, hi4 = l >> 4;
  const ushort* qg = qbuf + (size_t)bh * 208 * 64;
  const ushort* kg = kbuf + (size_t)bh * 208 * 64;
  const ushort* vg = vtb + (size_t)bh * 80 * 232;
  const float*  ktp = ktb + (size_t)bh * 208;
  const float invs = 0.03608439182435161f;
  ushort* pw = &sP[w][0];

  int qrow = (rt * 16 + lr) * 64 + hi4 * 8;
  f16x8 q0 = *(const f16x8*)&qg[qrow];
  f16x8 q1 = *(const f16x8*)&qg[qrow + 32];
  float qt4[4];
  #pragma unroll
  for (int j = 0; j < 4; ++j) qt4[j] = qtb[(size_t)bh * 208 + rt * 16 + hi4 * 4 + j];
  f32x4 acc[13];
  #pragma unroll
  for (int nt = 0; nt < 13; ++nt) {
    int kr = (nt * 16 + lr) * 64 + hi4 * 8;
    f16x8 k0 = *(const f16x8*)&kg[kr];
    f16x8 k1 = *(const f16x8*)&kg[kr + 32];
    acc[nt] = (f32x4){0.f, 0.f, 0.f, 0.f};
    acc[nt] = __builtin_amdgcn_mfma_f32_16x16x32_f16(q0, k0, acc[nt], 0, 0, 0);
    acc[nt] = __builtin_amdgcn_mfma_f32_16x16x32_f16(q1, k1, acc[nt], 0, 0, 0);
  }
  float mx[4] = {-1e30f, -1e30f, -1e30f, -1e30f};
  #pragma unroll
  for (int nt = 0; nt < 13; ++nt) {
    int cI = nt * 16 + lr;
    float ktc = ktp[cI];
    bool valid = (cI < 197);
    #pragma unroll
    for (int j = 0; j < 4; ++j) {
      float s = (2.f + 2.f * (acc[nt][j] - qt4[j] * ktc)) * invs;
      acc[nt][j] = s;
      if (valid) mx[j] = fmaxf(mx[j], s);
    }
  }
  #pragma unroll
  for (int j = 0; j < 4; ++j)
    #pragma unroll
    for (int m = 8; m; m >>= 1) mx[j] = fmaxf(mx[j], __shfl_xor(mx[j], m, 64));
  #pragma unroll
  for (int nt = 0; nt < 14; ++nt) {
    int cI = nt * 16 + lr;
    #pragma unroll
    for (int j = 0; j < 4; ++j) {
      float p = (nt < 13 && cI < 197) ? __expf(acc[nt][j] - mx[j]) : 0.f;
      pw[(hi4 * 4 + j) * 248 + cI] = h_us(p);
    }
  }
  f32x4 accO[5];
  #pragma unroll
  for (int et = 0; et < 5; ++et) accO[et] = (f32x4){0.f, 0.f, 0.f, 0.f};
  #pragma unroll
  for (int ks = 0; ks < 7; ++ks) {
    f16x8 pa = *(const f16x8*)&pw[lr * 248 + ks * 32 + hi4 * 8];
    #pragma unroll
    for (int et = 0; et < 5; ++et) {
      int er = et * 16 + lr;
      f16x8 bv = *(const f16x8*)&vg[(er > 64 ? 64 : er) * 232 + ks * 32 + hi4 * 8];
      accO[et] = __builtin_amdgcn_mfma_f32_16x16x32_f16(pa, bv, accO[et], 0, 0, 0);
    }
  }
  float ssq[4] = {0.f, 0.f, 0.f, 0.f};
  #pragma unroll
  for (int et = 0; et < 4; ++et)
    #pragma unroll
    for (int j = 0; j < 4; ++j) ssq[j] += accO[et][j] * accO[et][j];
  if (lr == 0) {
    #pragma unroll
    for (int j = 0; j < 4; ++j) ssq[j] += accO[4][j] * accO[4][j];
  }
  #pragma unroll
  for (int j = 0; j < 4; ++j)
    #pragma unroll
    for (int m = 8; m; m >>= 1) ssq[j] += __shfl_xor(ssq[j], m, 64);
  float rf4[4];
  #pragma unroll
  for (int j = 0; j < 4; ++j) {
    float o0 = __shfl(accO[0][j], (l & 48));
    rf4[j] = rsqrtf(fmaxf(2.f * o0 * o0 - ssq[j], 1e-6f));
  }
  #pragma unroll
  for (int et = 0; et < 5; ++et) {
    int e = et * 16 + lr;
    if (e == 0 || e >= 65) continue;
    #pragma unroll
    for (int j = 0; j < 4; ++j) {
      int n = rt * 16 + hi4 * 4 + j;
      if (n < 197)
        outa[((size_t)(b * 197 + n)) * 768 + hd * 64 + (e - 1)] = h_us(accO[et][j] * rf4[j]);
    }
  }
}

// ---------------- fused lresnet + LN: wave-per-row, barrier-free ----------------
template<int FIN>
__global__ __launch_bounds__(256) void k_resnet_ln(ushort* __restrict__ tok, const ushort* __restrict__ s,
                                                   const float* __restrict__ wyp, int l,
                                                   const float* __restrict__ g, const float* __restrict__ bb,
                                                   ushort* __restrict__ out16, float* __restrict__ out32) {
  int w = threadIdx.x >> 6, lane = threadIdx.x & 63;
  int r = blockIdx.x * 4 + w;         // NTOK = 1576*4 exactly
  float wv = wyp[l];
  const ushort* sp = s + (size_t)r * 768;
  ushort* tp = tok + (size_t)r * 768;
  float sv[12], zv[12];
  float qs = 0.f;
  #pragma unroll
  for (int i = 0; i < 12; ++i) {
    int j = lane + 64 * i;
    float si = (j < 767) ? us_f(sp[j]) : 0.f;
    sv[i] = si; qs += si * si;
  }
  #pragma unroll
  for (int m = 32; m; m >>= 1) qs += __shfl_xor(qs, m, 64);
  float at = sqrtf(fmaxf(qs + 1.f, 1e-6f));
  float zs = 0.f;
  #pragma unroll
  for (int i = 0; i < 12; ++i) {
    int j = lane + 64 * i;
    float zi = (j < 767) ? (us_f(tp[1 + j]) + wv * sv[i]) : 0.f;
    zv[i] = zi; zs += zi * zi;
  }
  #pragma unroll
  for (int m = 32; m; m >>= 1) zs += __shfl_xor(zs, m, 64);
  float zt = us_f(tp[0]) + wv * at;
  float rf = rsqrtf(fmaxf(zt * zt - zs, 1e-6f));
  float sm = 0.f, sq = 0.f;
  #pragma unroll
  for (int i = 0; i < 12; ++i) {
    float ni = zv[i] * rf;
    zv[i] = ni;
    int j = lane + 64 * i;
    if (j < 767) tp[1 + j] = h_us(ni);
    sm += ni; sq += ni * ni;
  }
  if (lane == 0) tp[0] = h_us(zt * rf);
  #pragma unroll
  for (int m = 32; m; m >>= 1) { sm += __shfl_xor(sm, m, 64); sq += __shfl_xor(sq, m, 64); }
  float mu = sm * (1.f / 767.f);
  float rstd = rsqrtf(fmaxf(sq * (1.f / 767.f) - mu * mu, 0.f) + 1e-6f);
  if (FIN) {
    float yv[12];
    float qq = 0.f;
    #pragma unroll
    for (int i = 0; i < 12; ++i) {
      int j = lane + 64 * i;
      float y = (j < 767) ? ((zv[i] - mu) * rstd * g[j] + bb[j]) : 0.f;
      yv[i] = y; qq += y * y;
    }
    #pragma unroll
    for (int m = 32; m; m >>= 1) qq += __shfl_xor(qq, m, 64);
    float* op = out32 + (size_t)r * 768;
    #pragma unroll
    for (int i = 0; i < 12; ++i) {
      int j = lane + 64 * i;
      if (j < 767) op[1 + j] = yv[i];
    }
    if (lane == 0) op[0] = sqrtf(fmaxf(qq + 1.f, 1e-6f));
  } else {
    size_t o = (size_t)r * 768;
    #pragma unroll
    for (int i = 0; i < 12; ++i) {
      int j = lane + 64 * i;
      if (j < 767) out16[o + j] = h_us((zv[i] - mu) * rstd * g[j] + bb[j]);
      else if (j == 767) out16[o + 767] = 0;
    }
  }
}

extern "C" void kernel_launch(void* const* d_in, const int* in_sizes, int n_in,
                              void* d_out, int out_size, void* d_ws, size_t ws_size,
                              hipStream_t stream) {
  const float* x     = (const float*)d_in[0];
  const float* cls_s = (const float*)d_in[1];
  const float* Wp    = (const float*)d_in[2];
  const float* ln1g  = (const float*)d_in[3];
  const float* ln1b  = (const float*)d_in[4];
  const float* Wq    = (const float*)d_in[5];
  const float* Wk    = (const float*)d_in[6];
  const float* Wv    = (const float*)d_in[7];
  const float* Wo    = (const float*)d_in[8];
  const float* ln2g  = (const float*)d_in[9];
  const float* ln2b  = (const float*)d_in[10];
  const float* W1    = (const float*)d_in[11];
  const float* W2    = (const float*)d_in[12];
  const float* W3    = (const float*)d_in[13];
  const float* wy1   = (const float*)d_in[14];
  const float* wy2   = (const float*)d_in[15];
  const float* lnfg  = (const float*)d_in[16];
  const float* lnfb  = (const float*)d_in[17];

  if (ws_size < B_END) return;

  char* ws = (char*)d_ws;
  float*  cosb   = (float*)(ws + B_COS);
  float*  sinb   = (float*)(ws + B_SIN);
  ushort* wpt    = (ushort*)(ws + B_WPT);
  ushort* apatch = (ushort*)(ws + B_APATCH);
  ushort* wqkvt  = (ushort*)(ws + B_WQKVT);
  ushort* wot    = (ushort*)(ws + B_WOT);
  ushort* w12t   = (ushort*)(ws + B_W12T);
  ushort* w3t    = (ushort*)(ws + B_W3T);
  ushort* tok    = (ushort*)(ws + B_TOK);
  ushort* acta   = (ushort*)(ws + B_ACTA);
  ushort* actb   = (ushort*)(ws + B_ACTB);
  float*  gout   = (float*)(ws + B_GOUT);
  ushort* gouth  = (ushort*)(ws + B_GOUT);
  ushort* qbuf   = (ushort*)(ws + B_QB);
  ushort* kbuf   = (ushort*)(ws + B_KB);
  ushort* vtb    = (ushort*)(ws + B_VT);
  float*  qtb    = (float*)(ws + B_QTB);
  float*  ktb    = (float*)(ws + B_KTB);

  // only V pads must be zero (P=0 x garbage would still contribute via PV MFMA).
  hipMemsetAsync(vtb, 0, VELE * 2, stream);

  k_rope_tab<<<25, 256, 0, stream>>>(cosb, sinb);
  k_tpose<<<32 * 24, 256, 0, stream>>>(Wp, wpt, 1024, 767, 32, 1024);
  k_im2col<<<CONVM, 256, 0, stream>>>(x, apatch);
  k_wprep12<<<3456 * NLAYER, 256, 0, stream>>>(Wq, Wk, Wv, Wo, W1, W2, W3, wqkvt, wot, w12t, w3t);
  k_gemmh<0, 4><<<dim3(49, 6), 256, 0, stream>>>(apatch, wpt, gout, nullptr, 768, 1024);
  k_build_tok<<<NTOK, 256, 0, stream>>>(gout, cls_s, tok);
  k_ln<<<NTOK, 256, 0, stream>>>(tok, ln1g, ln1b, acta);

  for (int l = 0; l < NLAYER; ++l) {
    const ushort* wq_l  = wqkvt + (size_t)l * WS_QKV;
    const ushort* wo_l  = wot   + (size_t)l * WS_WO;
    const ushort* w12_l = w12t  + (size_t)l * WS_W12;
    const ushort* w3_l  = w3t   + (size_t)l * WS_W3;

    k_g256<2><<<dim3(25, 9), 512, 0, stream>>>(acta, wq_l, nullptr, 2304, 768,
                                               qbuf, kbuf, vtb, qtb, ktb, cosb, sinb);
    k_attn<<<dim3(7, 384), 128, 0, stream>>>(qbuf, qtb, kbuf, ktb, vtb, acta);
    k_gemmh<3, 2><<<dim3(50, 12), 256, 0, stream>>>(acta, wo_l, nullptr, gouth, 768, 768);
    k_resnet_ln<0><<<1576, 256, 0, stream>>>(tok, gouth, wy1, l,
                                             ln2g + (size_t)l * 767, ln2b + (size_t)l * 767, acta, nullptr);

    k_gemmh<1, 4><<<dim3(50, 32), 256, 0, stream>>>(acta, w12_l, nullptr, actb, 4096, 768);
    k_gemmh<3, 2><<<dim3(50, 12), 256, 0, stream>>>(actb, w3_l, nullptr, gouth, 768, 2048);
    if (l < NLAYER - 1)
      k_resnet_ln<0><<<1576, 256, 0, stream>>>(tok, gouth, wy2, l,
                                               ln1g + (size_t)(l + 1) * 767, ln1b + (size_t)(l + 1) * 767,
                                               acta, nullptr);
    else
      k_resnet_ln<1><<<1576, 256, 0, stream>>>(tok, gouth, wy2, l, lnfg, lnfb, nullptr, (float*)d_out);
  }
}